// Round 7
// baseline (289.484 us; speedup 1.0000x reference)
//
#include <hip/hip_runtime.h>
#include <cstdint>
#include <cstddef>

#define T_SEQ 2048
#define B_SZ  2
#define EMB   2048
#define NH    16
#define NKV   4
#define HD    128
#define KVD   512
#define QKVN  3072
#define MROWS (B_SZ*T_SEQ)

typedef __bf16 bf16x8 __attribute__((ext_vector_type(8)));
typedef float  f32x4  __attribute__((ext_vector_type(4)));
typedef short  s16x8  __attribute__((ext_vector_type(8)));
typedef unsigned short u16;

__device__ __forceinline__ u16 f2b(float f) {
  uint32_t u = __builtin_bit_cast(uint32_t, f);
  u += 0x7fffu + ((u >> 16) & 1u);      // RNE
  return (u16)(u >> 16);
}
__device__ __forceinline__ float b2f(u16 h) {
  return __builtin_bit_cast(float, (uint32_t)h << 16);
}
__device__ __forceinline__ bf16x8 ld_bf8(const u16* p) {
  return __builtin_bit_cast(bf16x8, *(const s16x8*)p);
}
__device__ __forceinline__ void glds16(const void* g, void* l) {
  __builtin_amdgcn_global_load_lds((const __attribute__((address_space(1))) void*)g,
                                   (__attribute__((address_space(3))) void*)l, 16, 0, 0);
}
template<int N> __device__ __forceinline__ void waitv() {
  if constexpr (N == 0) asm volatile("s_waitcnt vmcnt(0)" ::: "memory");
  else if constexpr (N == 2) asm volatile("s_waitcnt vmcnt(2)" ::: "memory");
  else if constexpr (N == 3) asm volatile("s_waitcnt vmcnt(3)" ::: "memory");
  __builtin_amdgcn_sched_barrier(0);
}

// ---------------- fp32 -> bf16 elementwise ----------------
__global__ void cvt_x_kernel(const float4* __restrict__ x, ushort4* __restrict__ xb, int n4) {
  int i = blockIdx.x*blockDim.x + threadIdx.x;
  if (i >= n4) return;
  float4 v = x[i];
  ushort4 o;
  o.x = f2b(v.x); o.y = f2b(v.y); o.z = f2b(v.z); o.w = f2b(v.w);
  xb[i] = o;
}

// ---------------- fp32 (R x C) -> bf16 transposed (C x R), vectorized -------
__global__ void transpose_w_kernel(const float* __restrict__ in, u16* __restrict__ out,
                                   int R, int C) {
  __shared__ float tile[64][65];
  int c0 = blockIdx.x*64, r0 = blockIdx.y*64;
  int tx = threadIdx.x, ty = threadIdx.y;   // 16,16
#pragma unroll
  for (int k = 0; k < 4; ++k) {
    int r = ty + k*16;
    float4 v = *(const float4*)&in[(size_t)(r0+r)*C + c0 + tx*4];
    tile[r][tx*4+0] = v.x; tile[r][tx*4+1] = v.y;
    tile[r][tx*4+2] = v.z; tile[r][tx*4+3] = v.w;
  }
  __syncthreads();
#pragma unroll
  for (int k = 0; k < 4; ++k) {
    int c = ty + k*16;                      // output row = original col
    ushort4 o;
    o.x = f2b(tile[tx*4+0][c]);
    o.y = f2b(tile[tx*4+1][c]);
    o.z = f2b(tile[tx*4+2][c]);
    o.w = f2b(tile[tx*4+3][c]);
    *(ushort4*)&out[(size_t)(c0+c)*R + r0 + tx*4] = o;
  }
}

// ---------------- bf16 GEMM, 256xBN tile, 8-phase counted-vmcnt schedule ----
// (unchanged from r2 — verified: 256 blocks = 1/CU for both instantiations)
template<int BN, int WGN, int MF, int NF, int NF1, int SB, int SB1, int VMC, bool BF16_OUT>
__global__ __launch_bounds__(512, 2) void gemm_kernel(const u16* __restrict__ A,
        const u16* __restrict__ Bt, const float* __restrict__ bias,
        void* __restrict__ Cout, int M, int N, int K) {
  constexpr int MF2 = MF/2;
  __shared__ u16 As[2][256*64];
  __shared__ u16 Bs[2][BN*64];
  const int tid = threadIdx.x;
  const int w = tid >> 6, lane = tid & 63;
  const int quad = lane >> 4, lc = lane & 15;
  const int wrow = w / WGN, wcol = w % WGN;
  const int gx = gridDim.x;
  const int lin = blockIdx.y*gx + blockIdx.x;
  const int swz = (lin & 7)*32 + (lin >> 3);
  const int m0 = (swz / gx)*256, n0 = (swz % gx)*BN;

  f32x4 acc[MF][NF] = {};
  bf16x8 af[MF2][2], bfv[NF][2];

  int xoff[2];
#pragma unroll
  for (int ks = 0; ks < 2; ++ks) xoff[ks] = ((ks*4 + quad) ^ (lc & 7))*8;
  const int arow0 = (wrow*MF*16 + lc)*64;
  const int brow0 = (wcol*NF*16 + lc)*64;

  const int srb  = tid >> 3;
  const int spos = (tid & 7) ^ (srb & 7);
  const u16* sAp = A  + (size_t)(m0 + srb)*K + spos*8;
  const u16* sBp = Bt + (size_t)(n0 + srb)*K + spos*8;

#define STAGE_A(bf_, t_, h_) do { \
    glds16(sAp + (size_t)((h_)*2  )*64*K + (size_t)(t_)*64, &As[bf_][((h_)*2  )*4096 + w*512]); \
    glds16(sAp + (size_t)((h_)*2+1)*64*K + (size_t)(t_)*64, &As[bf_][((h_)*2+1)*4096 + w*512]); \
  } while (0)
#define STAGE_B(bf_, t_, p_) do { \
    _Pragma("unroll") for (int r = (p_) ? SB1 : 0; r < ((p_) ? SB : SB1); ++r) \
      glds16(sBp + (size_t)r*64*K + (size_t)(t_)*64, &Bs[bf_][r*4096 + w*512]); \
  } while (0)
#define LDAH(S_, h_) do { _Pragma("unroll") for (int i = 0; i < MF2; ++i) { \
    af[i][0] = ld_bf8((S_) + arow0 + ((h_)*MF2 + i)*1024 + xoff[0]); \
    af[i][1] = ld_bf8((S_) + arow0 + ((h_)*MF2 + i)*1024 + xoff[1]); } } while (0)
#define LDBG(S_, g_) do { _Pragma("unroll") for (int j = (g_) ? NF1 : 0; j < ((g_) ? NF : NF1); ++j) { \
    bfv[j][0] = ld_bf8((S_) + brow0 + j*1024 + xoff[0]); \
    bfv[j][1] = ld_bf8((S_) + brow0 + j*1024 + xoff[1]); } } while (0)
#define CL(h_, g_) do { _Pragma("unroll") for (int ks = 0; ks < 2; ++ks) \
    _Pragma("unroll") for (int i = 0; i < MF2; ++i) \
    _Pragma("unroll") for (int j = (g_) ? NF1 : 0; j < ((g_) ? NF : NF1); ++j) \
      acc[(h_)*MF2+i][j] = __builtin_amdgcn_mfma_f32_16x16x32_bf16( \
          af[i][ks], bfv[j][ks], acc[(h_)*MF2+i][j], 0, 0, 0); } while (0)
#define BARX()  __builtin_amdgcn_s_barrier()
#define SCHB()  __builtin_amdgcn_sched_barrier(0)
#define MFMAPH(h_, g_) do { BARX(); \
    asm volatile("s_waitcnt lgkmcnt(0)" ::: "memory"); SCHB(); \
    __builtin_amdgcn_s_setprio(1); CL(h_, g_); __builtin_amdgcn_s_setprio(0); \
  } while (0)

  const int NT = K >> 6;
  STAGE_B(0, 0, 0); STAGE_B(0, 0, 1);
  STAGE_A(0, 0, 0); STAGE_A(0, 0, 1);
  STAGE_B(1, 1, 0); STAGE_B(1, 1, 1);
  waitv<VMC>();
  BARX(); SCHB();

  for (int t0 = 0; t0 < NT-2; t0 += 2) {
    const u16 *a0 = As[0], *b0 = Bs[0], *a1 = As[1], *b1 = Bs[1];
    LDAH(a0, 0); LDBG(b0, 0); STAGE_A(1, t0+1, 0);
    MFMAPH(0, 0); BARX();
    LDBG(b0, 1); STAGE_A(1, t0+1, 1);
    MFMAPH(0, 1); BARX();
    LDAH(a0, 1); STAGE_B(0, t0+2, 0);
    MFMAPH(1, 0); BARX();
    STAGE_B(0, t0+2, 1);
    MFMAPH(1, 1);
    waitv<VMC>();
    BARX(); SCHB();
    LDAH(a1, 0); LDBG(b1, 0); STAGE_A(0, t0+2, 0);
    MFMAPH(0, 0); BARX();
    LDBG(b1, 1); STAGE_A(0, t0+2, 1);
    MFMAPH(0, 1); BARX();
    LDAH(a1, 1); STAGE_B(1, t0+3, 0);
    MFMAPH(1, 0); BARX();
    STAGE_B(1, t0+3, 1);
    MFMAPH(1, 1);
    waitv<VMC>();
    BARX(); SCHB();
  }
  {
    const u16 *a0 = As[0], *b0 = Bs[0], *a1 = As[1], *b1 = Bs[1];
    LDAH(a0, 0); LDBG(b0, 0); STAGE_A(1, NT-1, 0);
    MFMAPH(0, 0); BARX();
    LDBG(b0, 1); STAGE_A(1, NT-1, 1);
    MFMAPH(0, 1); BARX();
    LDAH(a0, 1);
    MFMAPH(1, 0); BARX();
    MFMAPH(1, 1);
    waitv<0>();
    BARX(); SCHB();
    LDAH(a1, 0); LDBG(b1, 0);
    MFMAPH(0, 0); BARX();
    LDBG(b1, 1);
    MFMAPH(0, 1); BARX();
    LDAH(a1, 1);
    MFMAPH(1, 0); BARX();
    MFMAPH(1, 1);
  }

#undef STAGE_A
#undef STAGE_B
#undef LDAH
#undef LDBG
#undef CL
#undef BARX
#undef SCHB
#undef MFMAPH

#pragma unroll
  for (int j = 0; j < NF; ++j) {
    int col = n0 + wcol*NF*16 + j*16 + lc;
    float bv = BF16_OUT ? bias[col] : 0.0f;
#pragma unroll
    for (int i = 0; i < MF; ++i) {
      int rowb = m0 + wrow*MF*16 + i*16 + quad*4;
#pragma unroll
      for (int r = 0; r < 4; ++r) {
        float v = acc[i][j][r] + bv;
        if (BF16_OUT) ((u16*)Cout)[(size_t)(rowb+r)*N + col] = f2b(v);
        else          ((float*)Cout)[(size_t)(rowb+r)*N + col] = v;
      }
    }
  }
}

// ---------------- RoPE on K and V (reference ropes V too, not Q) ----------------
__global__ void rope_kernel(const u16* __restrict__ qkv, const float* __restrict__ fc,
                            const float* __restrict__ fs, u16* __restrict__ kout,
                            u16* __restrict__ vout) {
  int tid = threadIdx.x;
  int row = blockIdx.x;             // b*T + t
  int i = tid & 63, kv = tid >> 6;  // pair index, kv head
  int t = row & (T_SEQ-1);
  const u16* p = qkv + (size_t)row*QKVN + EMB + kv*HD + 2*i;
  float ka = b2f(p[0]),   kb = b2f(p[1]);
  float va = b2f(p[KVD]), vb = b2f(p[KVD+1]);
  float c = fc[t*64+i], s = fs[t*64+i];
  size_t ob = (size_t)row*KVD + kv*HD + 2*i;
  kout[ob]   = f2b(ka*c - kb*s);
  kout[ob+1] = f2b(ka*s + kb*c);
  vout[ob]   = f2b(va*c - vb*s);
  vout[ob+1] = f2b(va*s + vb*c);
}

// ---------------- V (b,t,kv,d) -> Vt (b,kv,d,t) ----------------
__global__ void transpose_v_kernel(const u16* __restrict__ vb, u16* __restrict__ vtb) {
  __shared__ u16 tile[32][33];
  int bkv = blockIdx.z;
  int b = bkv >> 2, kv = bkv & 3;
  int d0 = blockIdx.y*32, t0 = blockIdx.x*32;
  int tx = threadIdx.x, ty = threadIdx.y;
#pragma unroll
  for (int i = 0; i < 32; i += 8)
    tile[ty+i][tx] = vb[(size_t)(b*T_SEQ + t0+ty+i)*KVD + kv*HD + d0 + tx];
  __syncthreads();
#pragma unroll
  for (int i = 0; i < 32; i += 8)
    vtb[(size_t)(bkv*HD + d0+ty+i)*T_SEQ + t0 + tx] = tile[tx][ty+i];
}

// ---------------- flash attention v9: adjacent 32q/wave, all-tiles-shared ---
// LDS-throughput model (r6 post-mortem): flash is bound by the per-CU LDS pipe
// (~50 DS instrs/tile/wave ~= 504 cyc; v7 total = 133K cyc/CU ~= measured).
// v9: each wave owns ADJACENT q-tiles {32g, 32g+16} (32-aligned => ntA==ntB),
// so K/V frag ds_reads are shared by both MFMA chains on EVERY tile: 32 b128
// reads now feed 64 MFMA (v7: 32 for 32). Tile-iters 12544 -> 8448. Predicted
// per-CU LDS time ~82K cyc ~= 34us ideal.
// Balance: nt varies 1..32; assuming round-robin XCD + CU-fill dispatch, CU c
// of an XCD hosts blocks g_=c and g_=c+32; mapping g_<32 -> gg=63-2g_ (desc
// odd), g_>=32 -> gg=2(g_-32) (asc even) pairs nt sums to a constant 33, with
// heavy blocks dispatched first as fallback.
__global__ __launch_bounds__(256, 2) void flash_kernel(const u16* __restrict__ qkv,
    const u16* __restrict__ kb, const u16* __restrict__ vtb, u16* __restrict__ yb) {
  __shared__ u16 Ks[2][64*128];          // 2 x 16 KB
  __shared__ u16 Vs[2][128*64];          // 2 x 16 KB
  __shared__ u16 Ps[4][16*64];           // 4 x 2 KB (chunk-XOR swizzled)
  const int tid = threadIdx.x;
  const int w = tid >> 6, lane = tid & 63;
  const int quad = lane >> 4, lc = lane & 15;
  const int bkv = blockIdx.x & 7;        // XCD-pinned (b,kv)
  const int g_  = blockIdx.x >> 3;       // 0..63
  const int gg  = (g_ < 32) ? (63 - 2*g_) : (2*(g_ - 32));  // balance map
  const int b = bkv >> 2, kv = bkv & 3;
  const int h = kv*4 + w;                // wave = one head of the group
  const int qbA = gg*32;                 // lower adjacent sub-tile
  const int qbB = gg*32 + 16;            // upper adjacent sub-tile

  // Q frags (A-layout) for both sub-tiles; no RoPE on Q
  bf16x8 qfA[4], qfB[4];
  {
    const u16* qpA = qkv + (size_t)(b*T_SEQ + qbA + lc)*QKVN + h*HD + quad*8;
    const u16* qpB = qkv + (size_t)(b*T_SEQ + qbB + lc)*QKVN + h*HD + quad*8;
#pragma unroll
    for (int ks = 0; ks < 4; ++ks) { qfA[ks] = ld_bf8(qpA + ks*32); qfB[ks] = ld_bf8(qpB + ks*32); }
  }

  f32x4 oA[8] = {}, oB[8] = {};
  float rsA[4] = {0.f,0.f,0.f,0.f}, rsB[4] = {0.f,0.f,0.f,0.f};
  const u16* kbase = kb  + (size_t)b*T_SEQ*KVD + kv*HD;
  const u16* vbase = vtb + (size_t)bkv*HD*T_SEQ;
  const int nt = (qbB + 16 + 63) >> 6;   // == ntA == ntB (32-aligned pair)
  const float cs = 0.08838834764831845f * 1.4426950408889634f;  // scale*log2(e)
  u16* pw = Ps[w];

  // fixed per-thread staging source pointers (source-side XOR swizzle)
  const u16* kptr[4];
  const u16* vptr[4];
#pragma unroll
  for (int rr = 0; rr < 4; ++rr) {
    int krow = (rr*4 + w)*4 + (lane >> 4);
    int kcc  = (lane & 15) ^ (krow & 15);
    kptr[rr] = kbase + (size_t)krow*KVD + kcc*8;
    int vrow = (rr*4 + w)*8 + (lane >> 3);
    int vcc  = (lane & 7) ^ (vrow & 7);
    vptr[rr] = vbase + (size_t)vrow*T_SEQ + vcc*8;
  }

  // per-lane swizzled chunk offsets
  int koff[4], voff[2], poff[2];
#pragma unroll
  for (int ks = 0; ks < 4; ++ks) koff[ks] = lc*128 + (((ks*4 + quad) ^ lc)*8);
#pragma unroll
  for (int ks = 0; ks < 2; ++ks) voff[ks] = lc*64 + (((ks*4 + quad) ^ (lc & 7))*8);
#pragma unroll
  for (int ks = 0; ks < 2; ++ks) poff[ks] = lc*64 + (((ks*4 + quad) ^ (lc & 7))*8);
  // P-write: row = quad*4+r, u16 addr = row*64 + ((nt2*2+(lc>>3))^(row&7))*8 + (lc&7)
  int pwb[4], pwx[4];
#pragma unroll
  for (int r = 0; r < 4; ++r) {
    pwb[r] = (quad*4 + r)*64 + (lc & 7);
    pwx[r] = (quad*4 + r) & 7;
  }
  const int pcc = lc >> 3;

  // prologue: stage tile 0 -> buf 0, publish
#pragma unroll
  for (int rr = 0; rr < 4; ++rr) glds16(kptr[rr], &Ks[0][(rr*4 + w)*512]);
#pragma unroll
  for (int rr = 0; rr < 4; ++rr) glds16(vptr[rr], &Vs[0][(rr*4 + w)*512]);
  asm volatile("s_waitcnt vmcnt(0)" ::: "memory");
  __builtin_amdgcn_sched_barrier(0);
  __builtin_amdgcn_s_barrier();
  __builtin_amdgcn_sched_barrier(0);

// softmax for one sub-tile: sc -> P(LDS) + rs accumulate
#define SMAX(SC_, QB_, RS_) do { \
    if (k0 + 63 > (QB_)) { \
      _Pragma("unroll") for (int nt2 = 0; nt2 < 4; ++nt2) { \
        int key = k0 + nt2*16 + lc; \
        int qrow = (QB_) + quad*4; \
        _Pragma("unroll") for (int r = 0; r < 4; ++r) { \
          float e = __builtin_amdgcn_exp2f(SC_[nt2][r]*cs); \
          float p = (key <= qrow + r) ? e : 0.0f; \
          RS_[r] += p; \
          pw[pwb[r] + ((nt2*2 + pcc) ^ pwx[r])*8] = f2b(p); \
        } \
      } \
    } else { \
      _Pragma("unroll") for (int nt2 = 0; nt2 < 4; ++nt2) \
        _Pragma("unroll") for (int r = 0; r < 4; ++r) { \
          float p = __builtin_amdgcn_exp2f(SC_[nt2][r]*cs); \
          RS_[r] += p; \
          pw[pwb[r] + ((nt2*2 + pcc) ^ pwx[r])*8] = f2b(p); \
        } \
    } \
  } while (0)

  for (int t = 0; t < nt; ++t) {
    const int cur = t & 1;
    // prefetch tile t+1 into the other buffer (protected by barrier(end t-1))
    if (t + 1 < nt) {
#pragma unroll
      for (int rr = 0; rr < 4; ++rr)
        glds16(kptr[rr] + (size_t)(t+1)*64*KVD, &Ks[cur^1][(rr*4 + w)*512]);
#pragma unroll
      for (int rr = 0; rr < 4; ++rr)
        glds16(vptr[rr] + (size_t)(t+1)*64,     &Vs[cur^1][(rr*4 + w)*512]);
    }
    const u16* ksb = Ks[cur];
    const u16* vsb = Vs[cur];
    const int k0 = t*64;

    // QK^T for both sub-tiles: K frags read ONCE, feed 2 MFMA chains
    f32x4 scA[4] = {}, scB[4] = {};
    __builtin_amdgcn_s_setprio(1);
#pragma unroll
    for (int nt2 = 0; nt2 < 4; ++nt2) {
      bf16x8 kf[4];
#pragma unroll
      for (int ks = 0; ks < 4; ++ks)
        kf[ks] = ld_bf8(ksb + nt2*16*128 + koff[ks]);
#pragma unroll
      for (int ks = 0; ks < 4; ++ks) {
        scB[nt2] = __builtin_amdgcn_mfma_f32_16x16x32_bf16(qfB[ks], kf[ks], scB[nt2], 0, 0, 0);
        scA[nt2] = __builtin_amdgcn_mfma_f32_16x16x32_bf16(qfA[ks], kf[ks], scA[nt2], 0, 0, 0);
      }
    }
    __builtin_amdgcn_s_setprio(0);

    // softmax + P roundtrip: B then A through the same 2KB Ps (intra-wave
    // DS in-order; may-aliasing preserves write->read->write->read order)
    SMAX(scB, qbB, rsB);
    bf16x8 paB[2];
#pragma unroll
    for (int ks = 0; ks < 2; ++ks) paB[ks] = ld_bf8(pw + poff[ks]);
    SMAX(scA, qbA, rsA);
    bf16x8 paA[2];
#pragma unroll
    for (int ks = 0; ks < 2; ++ks) paA[ks] = ld_bf8(pw + poff[ks]);

    // O += P V for both sub-tiles: V frags read ONCE
    __builtin_amdgcn_s_setprio(1);
#pragma unroll
    for (int j = 0; j < 8; ++j) {
      bf16x8 vf0 = ld_bf8(vsb + j*16*64 + voff[0]);
      bf16x8 vf1 = ld_bf8(vsb + j*16*64 + voff[1]);
      oB[j] = __builtin_amdgcn_mfma_f32_16x16x32_bf16(paB[0], vf0, oB[j], 0, 0, 0);
      oB[j] = __builtin_amdgcn_mfma_f32_16x16x32_bf16(paB[1], vf1, oB[j], 0, 0, 0);
      oA[j] = __builtin_amdgcn_mfma_f32_16x16x32_bf16(paA[0], vf0, oA[j], 0, 0, 0);
      oA[j] = __builtin_amdgcn_mfma_f32_16x16x32_bf16(paA[1], vf1, oA[j], 0, 0, 0);
    }
    __builtin_amdgcn_s_setprio(0);

    // publish prefetched tile: own loads drained, then block-wide sync
    asm volatile("s_waitcnt vmcnt(0)" ::: "memory");
    __builtin_amdgcn_sched_barrier(0);
    __builtin_amdgcn_s_barrier();
    __builtin_amdgcn_sched_barrier(0);
  }
#undef SMAX

  // epilogue: l-reduce over the 16 key-lanes, normalize, store (both sub-tiles)
#pragma unroll
  for (int r = 0; r < 4; ++r) {
    float vA = rsA[r], vB = rsB[r];
#pragma unroll
    for (int off2 = 8; off2 >= 1; off2 >>= 1) {
      vA += __shfl_xor(vA, off2);
      vB += __shfl_xor(vB, off2);
    }
    float invA = 1.0f / vA, invB = 1.0f / vB;
    size_t orowA = (size_t)(b*T_SEQ + qbA + quad*4 + r)*EMB + h*HD;
    size_t orowB = (size_t)(b*T_SEQ + qbB + quad*4 + r)*EMB + h*HD;
#pragma unroll
    for (int j = 0; j < 8; ++j) {
      yb[orowA + j*16 + lc] = f2b(oA[j][r]*invA);
      yb[orowB + j*16 + lc] = f2b(oB[j][r]*invB);
    }
  }
}

extern "C" void kernel_launch(void* const* d_in, const int* in_sizes, int n_in,
                              void* d_out, int out_size, void* d_ws, size_t ws_size,
                              hipStream_t stream) {
  const float* x      = (const float*)d_in[0];
  const float* W_attn = (const float*)d_in[1];
  const float* b_attn = (const float*)d_in[2];
  const float* W_proj = (const float*)d_in[3];
  const float* fc     = (const float*)d_in[4];
  const float* fs     = (const float*)d_in[5];

  u16* ws   = (u16*)d_ws;
  u16* xb   = ws;                          // 8.39M elems  (later aliased by yb)
  u16* WaT  = xb   + (size_t)MROWS*EMB;    // 6.29M        (later aliased by WpT)
  u16* qkv  = WaT  + (size_t)QKVN*EMB;     // 12.58M
  u16* kbuf = qkv  + (size_t)MROWS*QKVN;   // 2.10M
  u16* vb   = kbuf + (size_t)MROWS*KVD;    // 2.10M
  u16* vtb  = vb   + (size_t)MROWS*KVD;    // 2.10M  -> total 67.1 MB
  u16* WpT  = WaT;   // W_attn^T dead after gemm1
  u16* yb   = xb;    // x_bf16 dead after gemm1
  float* out = (float*)d_out;

  cvt_x_kernel<<<(MROWS*EMB/4 + 255)/256, 256, 0, stream>>>(
      (const float4*)x, (ushort4*)xb, MROWS*EMB/4);
  transpose_w_kernel<<<dim3(QKVN/64, EMB/64), dim3(16, 16), 0, stream>>>(
      W_attn, WaT, EMB, QKVN);
  // gemm1: 256x192 tiles -> 16x16 = 256 blocks (1/CU)
  gemm_kernel<192, 4, 8, 3, 2, 3, 2, 3, true>
      <<<dim3(QKVN/192, MROWS/256), 512, 0, stream>>>(
      xb, WaT, b_attn, qkv, MROWS, QKVN, EMB);
  rope_kernel<<<MROWS, 256, 0, stream>>>(qkv, fc, fs, kbuf, vb);
  transpose_v_kernel<<<dim3(T_SEQ/32, HD/32, B_SZ*NKV), dim3(32, 8), 0, stream>>>(vb, vtb);
  transpose_w_kernel<<<dim3(EMB/64, EMB/64), dim3(16, 16), 0, stream>>>(
      W_proj, WpT, EMB, EMB);
  // flash v9: 512 blocks (all resident, 2/CU), 4 waves = 4 heads,
  // each wave = adjacent q-tile pair {32g, 32g+16} with balance mapping
  flash_kernel<<<dim3(B_SZ*NKV*(T_SEQ/32)), 256, 0, stream>>>(qkv, kbuf, vtb, yb);
  // gemm2: 256x128 tiles -> 16x16 = 256 blocks (1/CU)
  gemm_kernel<128, 2, 4, 4, 2, 2, 1, 2, false>
      <<<dim3(EMB/128, MROWS/256), 512, 0, stream>>>(
      yb, WpT, nullptr, out, MROWS, EMB, EMB);
}

// Round 8
// 278.791 us; speedup vs baseline: 1.0384x; 1.0384x over previous
//
#include <hip/hip_runtime.h>
#include <cstdint>
#include <cstddef>

#define T_SEQ 2048
#define B_SZ  2
#define EMB   2048
#define NH    16
#define NKV   4
#define HD    128
#define KVD   512
#define QKVN  3072
#define MROWS (B_SZ*T_SEQ)

typedef __bf16 bf16x8 __attribute__((ext_vector_type(8)));
typedef float  f32x4  __attribute__((ext_vector_type(4)));
typedef short  s16x8  __attribute__((ext_vector_type(8)));
typedef unsigned short u16;

__device__ __forceinline__ u16 f2b(float f) {
  uint32_t u = __builtin_bit_cast(uint32_t, f);
  u += 0x7fffu + ((u >> 16) & 1u);      // RNE
  return (u16)(u >> 16);
}
__device__ __forceinline__ float b2f(u16 h) {
  return __builtin_bit_cast(float, (uint32_t)h << 16);
}
__device__ __forceinline__ bf16x8 ld_bf8(const u16* p) {
  return __builtin_bit_cast(bf16x8, *(const s16x8*)p);
}
__device__ __forceinline__ void glds16(const void* g, void* l) {
  __builtin_amdgcn_global_load_lds((const __attribute__((address_space(1))) void*)g,
                                   (__attribute__((address_space(3))) void*)l, 16, 0, 0);
}
template<int N> __device__ __forceinline__ void waitv() {
  if constexpr (N == 0) asm volatile("s_waitcnt vmcnt(0)" ::: "memory");
  else if constexpr (N == 2) asm volatile("s_waitcnt vmcnt(2)" ::: "memory");
  else if constexpr (N == 3) asm volatile("s_waitcnt vmcnt(3)" ::: "memory");
  __builtin_amdgcn_sched_barrier(0);
}

// ---------------- fused prep: fp32->bf16 cvt + W_attn transpose -------------
// Launch-gap reduction: 2 independent preprocessing kernels in ONE launch,
// partitioned by blockIdx (no inter-part dependency).
#define CVT_BLKS (MROWS*EMB/4/256)      // 8192
#define TW1_BX   (QKVN/64)              // 48
#define TW1_BLKS (TW1_BX*(EMB/64))      // 1536
__global__ void prep_kernel(const float4* __restrict__ x, ushort4* __restrict__ xb,
                            const float* __restrict__ Wa, u16* __restrict__ WaT) {
  __shared__ float tile[64][65];
  const int bid = blockIdx.x, tid = threadIdx.x;
  if (bid < CVT_BLKS) {                 // ---- cvt_x part
    int i = bid*256 + tid;
    float4 v = x[i];
    ushort4 o;
    o.x = f2b(v.x); o.y = f2b(v.y); o.z = f2b(v.z); o.w = f2b(v.w);
    xb[i] = o;
    return;
  }
  // ---- W_attn (EMB x QKVN) -> bf16 transposed (QKVN x EMB)
  const int tb = bid - CVT_BLKS;
  const int C = QKVN, R = EMB;
  const int c0 = (tb % TW1_BX)*64, r0 = (tb / TW1_BX)*64;
  const int tx = tid & 15, ty = tid >> 4;
#pragma unroll
  for (int k = 0; k < 4; ++k) {
    int r = ty + k*16;
    float4 v = *(const float4*)&Wa[(size_t)(r0+r)*C + c0 + tx*4];
    tile[r][tx*4+0] = v.x; tile[r][tx*4+1] = v.y;
    tile[r][tx*4+2] = v.z; tile[r][tx*4+3] = v.w;
  }
  __syncthreads();
#pragma unroll
  for (int k = 0; k < 4; ++k) {
    int c = ty + k*16;
    ushort4 o;
    o.x = f2b(tile[tx*4+0][c]);
    o.y = f2b(tile[tx*4+1][c]);
    o.z = f2b(tile[tx*4+2][c]);
    o.w = f2b(tile[tx*4+3][c]);
    *(ushort4*)&WaT[(size_t)(c0+c)*R + r0 + tx*4] = o;
  }
}

// ---------------- bf16 GEMM, 256xBN tile, 8-phase counted-vmcnt schedule ----
// (unchanged from r2 — verified: 256 blocks = 1/CU for both instantiations)
template<int BN, int WGN, int MF, int NF, int NF1, int SB, int SB1, int VMC, bool BF16_OUT>
__global__ __launch_bounds__(512, 2) void gemm_kernel(const u16* __restrict__ A,
        const u16* __restrict__ Bt, const float* __restrict__ bias,
        void* __restrict__ Cout, int M, int N, int K) {
  constexpr int MF2 = MF/2;
  __shared__ u16 As[2][256*64];
  __shared__ u16 Bs[2][BN*64];
  const int tid = threadIdx.x;
  const int w = tid >> 6, lane = tid & 63;
  const int quad = lane >> 4, lc = lane & 15;
  const int wrow = w / WGN, wcol = w % WGN;
  const int gx = gridDim.x;
  const int lin = blockIdx.y*gx + blockIdx.x;
  const int swz = (lin & 7)*32 + (lin >> 3);
  const int m0 = (swz / gx)*256, n0 = (swz % gx)*BN;

  f32x4 acc[MF][NF] = {};
  bf16x8 af[MF2][2], bfv[NF][2];

  int xoff[2];
#pragma unroll
  for (int ks = 0; ks < 2; ++ks) xoff[ks] = ((ks*4 + quad) ^ (lc & 7))*8;
  const int arow0 = (wrow*MF*16 + lc)*64;
  const int brow0 = (wcol*NF*16 + lc)*64;

  const int srb  = tid >> 3;
  const int spos = (tid & 7) ^ (srb & 7);
  const u16* sAp = A  + (size_t)(m0 + srb)*K + spos*8;
  const u16* sBp = Bt + (size_t)(n0 + srb)*K + spos*8;

#define STAGE_A(bf_, t_, h_) do { \
    glds16(sAp + (size_t)((h_)*2  )*64*K + (size_t)(t_)*64, &As[bf_][((h_)*2  )*4096 + w*512]); \
    glds16(sAp + (size_t)((h_)*2+1)*64*K + (size_t)(t_)*64, &As[bf_][((h_)*2+1)*4096 + w*512]); \
  } while (0)
#define STAGE_B(bf_, t_, p_) do { \
    _Pragma("unroll") for (int r = (p_) ? SB1 : 0; r < ((p_) ? SB : SB1); ++r) \
      glds16(sBp + (size_t)r*64*K + (size_t)(t_)*64, &Bs[bf_][r*4096 + w*512]); \
  } while (0)
#define LDAH(S_, h_) do { _Pragma("unroll") for (int i = 0; i < MF2; ++i) { \
    af[i][0] = ld_bf8((S_) + arow0 + ((h_)*MF2 + i)*1024 + xoff[0]); \
    af[i][1] = ld_bf8((S_) + arow0 + ((h_)*MF2 + i)*1024 + xoff[1]); } } while (0)
#define LDBG(S_, g_) do { _Pragma("unroll") for (int j = (g_) ? NF1 : 0; j < ((g_) ? NF : NF1); ++j) { \
    bfv[j][0] = ld_bf8((S_) + brow0 + j*1024 + xoff[0]); \
    bfv[j][1] = ld_bf8((S_) + brow0 + j*1024 + xoff[1]); } } while (0)
#define CL(h_, g_) do { _Pragma("unroll") for (int ks = 0; ks < 2; ++ks) \
    _Pragma("unroll") for (int i = 0; i < MF2; ++i) \
    _Pragma("unroll") for (int j = (g_) ? NF1 : 0; j < ((g_) ? NF : NF1); ++j) \
      acc[(h_)*MF2+i][j] = __builtin_amdgcn_mfma_f32_16x16x32_bf16( \
          af[i][ks], bfv[j][ks], acc[(h_)*MF2+i][j], 0, 0, 0); } while (0)
#define BARX()  __builtin_amdgcn_s_barrier()
#define SCHB()  __builtin_amdgcn_sched_barrier(0)
#define MFMAPH(h_, g_) do { BARX(); \
    asm volatile("s_waitcnt lgkmcnt(0)" ::: "memory"); SCHB(); \
    __builtin_amdgcn_s_setprio(1); CL(h_, g_); __builtin_amdgcn_s_setprio(0); \
  } while (0)

  const int NT = K >> 6;
  STAGE_B(0, 0, 0); STAGE_B(0, 0, 1);
  STAGE_A(0, 0, 0); STAGE_A(0, 0, 1);
  STAGE_B(1, 1, 0); STAGE_B(1, 1, 1);
  waitv<VMC>();
  BARX(); SCHB();

  for (int t0 = 0; t0 < NT-2; t0 += 2) {
    const u16 *a0 = As[0], *b0 = Bs[0], *a1 = As[1], *b1 = Bs[1];
    LDAH(a0, 0); LDBG(b0, 0); STAGE_A(1, t0+1, 0);
    MFMAPH(0, 0); BARX();
    LDBG(b0, 1); STAGE_A(1, t0+1, 1);
    MFMAPH(0, 1); BARX();
    LDAH(a0, 1); STAGE_B(0, t0+2, 0);
    MFMAPH(1, 0); BARX();
    STAGE_B(0, t0+2, 1);
    MFMAPH(1, 1);
    waitv<VMC>();
    BARX(); SCHB();
    LDAH(a1, 0); LDBG(b1, 0); STAGE_A(0, t0+2, 0);
    MFMAPH(0, 0); BARX();
    LDBG(b1, 1); STAGE_A(0, t0+2, 1);
    MFMAPH(0, 1); BARX();
    LDAH(a1, 1); STAGE_B(1, t0+3, 0);
    MFMAPH(1, 0); BARX();
    STAGE_B(1, t0+3, 1);
    MFMAPH(1, 1);
    waitv<VMC>();
    BARX(); SCHB();
  }
  {
    const u16 *a0 = As[0], *b0 = Bs[0], *a1 = As[1], *b1 = Bs[1];
    LDAH(a0, 0); LDBG(b0, 0); STAGE_A(1, NT-1, 0);
    MFMAPH(0, 0); BARX();
    LDBG(b0, 1); STAGE_A(1, NT-1, 1);
    MFMAPH(0, 1); BARX();
    LDAH(a0, 1);
    MFMAPH(1, 0); BARX();
    MFMAPH(1, 1);
    waitv<0>();
    BARX(); SCHB();
    LDAH(a1, 0); LDBG(b1, 0);
    MFMAPH(0, 0); BARX();
    LDBG(b1, 1);
    MFMAPH(0, 1); BARX();
    LDAH(a1, 1);
    MFMAPH(1, 0); BARX();
    MFMAPH(1, 1);
  }

#undef STAGE_A
#undef STAGE_B
#undef LDAH
#undef LDBG
#undef CL
#undef BARX
#undef SCHB
#undef MFMAPH

#pragma unroll
  for (int j = 0; j < NF; ++j) {
    int col = n0 + wcol*NF*16 + j*16 + lc;
    float bv = BF16_OUT ? bias[col] : 0.0f;
#pragma unroll
    for (int i = 0; i < MF; ++i) {
      int rowb = m0 + wrow*MF*16 + i*16 + quad*4;
#pragma unroll
      for (int r = 0; r < 4; ++r) {
        float v = acc[i][j][r] + bv;
        if (BF16_OUT) ((u16*)Cout)[(size_t)(rowb+r)*N + col] = f2b(v);
        else          ((float*)Cout)[(size_t)(rowb+r)*N + col] = v;
      }
    }
  }
}

// ---------------- fused: RoPE(K,V) + V-transpose + W_proj transpose ---------
// Part 1 (RTV_BLKS blocks): block = (bkv, 32-row t-tile). Ropes K (coalesced
// out to kbuf) and V; transposes its OWN V tile via LDS -> vtb. All deps
// intra-block, so rope->transpose needs no second kernel, and the vb
// intermediate buffer round-trip (~17MB) disappears.
// Part 2: W_proj (EMB x EMB) -> bf16 transposed. WaT is dead after gemm1, so
// writing WpT (same buffer) here is legal (this kernel runs after gemm1).
#define RTV_BLKS (8*(T_SEQ/32))         // 512
#define TW2_BX   (EMB/64)               // 32
__global__ void ropetv_kernel(const u16* __restrict__ qkv, const float* __restrict__ fc,
                              const float* __restrict__ fs, u16* __restrict__ kout,
                              u16* __restrict__ vtb, const float* __restrict__ Wp,
                              u16* __restrict__ WpT) {
  __shared__ float tile[64][65];        // tw2 part
  __shared__ u16 vt[32][136];           // rtv part: [t][d], row stride 272B (17x16B)
  const int bid = blockIdx.x, tid = threadIdx.x;
  if (bid < RTV_BLKS) {
    const int bkv = bid & 7;
    const int t0 = (bid >> 3)*32;
    const int b = bkv >> 2, kv = bkv & 3;
    const int tl = tid >> 3, ch = tid & 7;   // 32 rows x 8 chunks of 16 u16
    const int t = t0 + tl;
    const int row = b*T_SEQ + t;
    const u16* p = qkv + (size_t)row*QKVN + EMB + kv*HD + ch*16;
    s16x8 kin0 = *(const s16x8*)p,        kin1 = *(const s16x8*)(p + 8);
    s16x8 vin0 = *(const s16x8*)(p + KVD), vin1 = *(const s16x8*)(p + KVD + 8);
    s16x8 ko0, ko1, vo0, vo1;
#pragma unroll
    for (int j = 0; j < 4; ++j) {            // pairs 0..3 (dims ch*16 + 2j)
      int i = ch*8 + j;
      float c = fc[t*64 + i], s = fs[t*64 + i];
      float ka = b2f((u16)kin0[2*j]), kb2 = b2f((u16)kin0[2*j+1]);
      float va = b2f((u16)vin0[2*j]), vb2 = b2f((u16)vin0[2*j+1]);
      ko0[2*j]   = (short)f2b(ka*c - kb2*s);
      ko0[2*j+1] = (short)f2b(ka*s + kb2*c);
      vo0[2*j]   = (short)f2b(va*c - vb2*s);
      vo0[2*j+1] = (short)f2b(va*s + vb2*c);
    }
#pragma unroll
    for (int j = 0; j < 4; ++j) {            // pairs 4..7 (dims ch*16 + 8 + 2j)
      int i = ch*8 + 4 + j;
      float c = fc[t*64 + i], s = fs[t*64 + i];
      float ka = b2f((u16)kin1[2*j]), kb2 = b2f((u16)kin1[2*j+1]);
      float va = b2f((u16)vin1[2*j]), vb2 = b2f((u16)vin1[2*j+1]);
      ko1[2*j]   = (short)f2b(ka*c - kb2*s);
      ko1[2*j+1] = (short)f2b(ka*s + kb2*c);
      vo1[2*j]   = (short)f2b(va*c - vb2*s);
      vo1[2*j+1] = (short)f2b(va*s + vb2*c);
    }
    u16* kq = kout + (size_t)row*KVD + kv*HD + ch*16;
    *(s16x8*)kq       = ko0;
    *(s16x8*)(kq + 8) = ko1;
    *(s16x8*)&vt[tl][ch*16]     = vo0;       // 16B aligned (272B row stride)
    *(s16x8*)&vt[tl][ch*16 + 8] = vo1;
    __syncthreads();
    // transpose out: thread = (d = tid>>1, half = tid&1); 32B per store
    const int d = tid >> 1, hf = tid & 1;
    u16 ov[16];
#pragma unroll
    for (int e = 0; e < 16; ++e) ov[e] = vt[hf*16 + e][d];
    u16* vq = vtb + (size_t)(bkv*HD + d)*T_SEQ + t0 + hf*16;
    *(s16x8*)vq       = *(s16x8*)&ov[0];
    *(s16x8*)(vq + 8) = *(s16x8*)&ov[8];
    return;
  }
  // ---- W_proj transpose part
  const int tb = bid - RTV_BLKS;
  const int C = EMB, R = EMB;
  const int c0 = (tb % TW2_BX)*64, r0 = (tb / TW2_BX)*64;
  const int tx = tid & 15, ty = tid >> 4;
#pragma unroll
  for (int k = 0; k < 4; ++k) {
    int r = ty + k*16;
    float4 v = *(const float4*)&Wp[(size_t)(r0+r)*C + c0 + tx*4];
    tile[r][tx*4+0] = v.x; tile[r][tx*4+1] = v.y;
    tile[r][tx*4+2] = v.z; tile[r][tx*4+3] = v.w;
  }
  __syncthreads();
#pragma unroll
  for (int k = 0; k < 4; ++k) {
    int c = ty + k*16;
    ushort4 o;
    o.x = f2b(tile[tx*4+0][c]);
    o.y = f2b(tile[tx*4+1][c]);
    o.z = f2b(tile[tx*4+2][c]);
    o.w = f2b(tile[tx*4+3][c]);
    *(ushort4*)&WpT[(size_t)(c0+c)*R + r0 + tx*4] = o;
  }
}

// ---------------- flash attention v7 (reverted best: 66.5us) ----------------
// One 256-thread block per (b, kv-group, 16-query tile); 4 waves = 4 Q-heads
// sharing staged K/V. Double-buffered prefetch-early loop + conflict-free
// chunk-XOR Ps. LDS = 72 KB -> 2 blocks/CU.
__global__ __launch_bounds__(256, 2) void flash_kernel(const u16* __restrict__ qkv,
    const u16* __restrict__ kb, const u16* __restrict__ vtb, u16* __restrict__ yb) {
  __shared__ u16 Ks[2][64*128];          // 2 x 16 KB
  __shared__ u16 Vs[2][128*64];          // 2 x 16 KB
  __shared__ u16 Ps[4][16*64];           // 4 x 2 KB (chunk-XOR swizzled)
  const int tid = threadIdx.x;
  const int w = tid >> 6, lane = tid & 63;
  const int quad = lane >> 4, lc = lane & 15;
  const int bkv = blockIdx.x & 7;        // XCD-pinned (b,kv)
  const int r_  = blockIdx.x >> 3;       // 0..127
  const int b = bkv >> 2, kv = bkv & 3;
  const int h = kv*4 + w;                // wave = one head of the group
  const int qbase = (127 - r_)*16;       // heavy q-tiles dispatch first

  // Q frags (A-layout) for 16 queries of head h; no RoPE on Q
  bf16x8 qf[4];
  {
    const u16* qp = qkv + (size_t)(b*T_SEQ + qbase + lc)*QKVN + h*HD + quad*8;
#pragma unroll
    for (int ks = 0; ks < 4; ++ks) qf[ks] = ld_bf8(qp + ks*32);
  }

  f32x4 o[8] = {};
  float rs[4] = {0.f, 0.f, 0.f, 0.f};
  const u16* kbase = kb  + (size_t)b*T_SEQ*KVD + kv*HD;
  const u16* vbase = vtb + (size_t)bkv*HD*T_SEQ;
  const int nk = qbase + 16;
  const int nt = (nk + 63) >> 6;
  const float cs = 0.08838834764831845f * 1.4426950408889634f;  // scale * log2(e)
  u16* pw = Ps[w];

  // fixed per-thread staging source pointers (source-side XOR swizzle)
  const u16* kptr[4];
  const u16* vptr[4];
#pragma unroll
  for (int rr = 0; rr < 4; ++rr) {
    int krow = (rr*4 + w)*4 + (lane >> 4);
    int kcc  = (lane & 15) ^ (krow & 15);
    kptr[rr] = kbase + (size_t)krow*KVD + kcc*8;
    int vrow = (rr*4 + w)*8 + (lane >> 3);
    int vcc  = (lane & 7) ^ (vrow & 7);
    vptr[rr] = vbase + (size_t)vrow*T_SEQ + vcc*8;
  }

  // per-lane swizzled chunk offsets (hoisted out of the K-loop)
  int koff[4], voff[2], poff[2];
#pragma unroll
  for (int ks = 0; ks < 4; ++ks) koff[ks] = lc*128 + (((ks*4 + quad) ^ lc)*8);
#pragma unroll
  for (int ks = 0; ks < 2; ++ks) voff[ks] = lc*64 + (((ks*4 + quad) ^ (lc & 7))*8);
#pragma unroll
  for (int ks = 0; ks < 2; ++ks) poff[ks] = lc*64 + (((ks*4 + quad) ^ (lc & 7))*8);
  // P-write: row = quad*4+r, u16 addr = row*64 + ((nt2*2+(lc>>3))^(row&7))*8 + (lc&7)
  int pwb[4], pwx[4];
#pragma unroll
  for (int r = 0; r < 4; ++r) {
    pwb[r] = (quad*4 + r)*64 + (lc & 7);
    pwx[r] = (quad*4 + r) & 7;
  }
  const int pcc = lc >> 3;

  // prologue: stage tile 0 -> buf 0, publish
#pragma unroll
  for (int rr = 0; rr < 4; ++rr) glds16(kptr[rr], &Ks[0][(rr*4 + w)*512]);
#pragma unroll
  for (int rr = 0; rr < 4; ++rr) glds16(vptr[rr], &Vs[0][(rr*4 + w)*512]);
  asm volatile("s_waitcnt vmcnt(0)" ::: "memory");
  __builtin_amdgcn_sched_barrier(0);
  __builtin_amdgcn_s_barrier();
  __builtin_amdgcn_sched_barrier(0);

  for (int t = 0; t < nt; ++t) {
    const int cur = t & 1;
    // prefetch tile t+1 into the other buffer (protected by barrier(end t-1))
    if (t + 1 < nt) {
#pragma unroll
      for (int rr = 0; rr < 4; ++rr)
        glds16(kptr[rr] + (size_t)(t+1)*64*KVD, &Ks[cur^1][(rr*4 + w)*512]);
#pragma unroll
      for (int rr = 0; rr < 4; ++rr)
        glds16(vptr[rr] + (size_t)(t+1)*64,     &Vs[cur^1][(rr*4 + w)*512]);
    }
    const u16* ksb = Ks[cur];
    const u16* vsb = Vs[cur];
    const int k0 = t*64;

    // S = Q K^T : 16 queries x 64 keys
    f32x4 sc[4] = {};
    __builtin_amdgcn_s_setprio(1);
#pragma unroll
    for (int nt2 = 0; nt2 < 4; ++nt2)
#pragma unroll
      for (int ks = 0; ks < 4; ++ks) {
        bf16x8 kf = ld_bf8(ksb + nt2*16*128 + koff[ks]);
        sc[nt2] = __builtin_amdgcn_mfma_f32_16x16x32_bf16(qf[ks], kf, sc[nt2], 0, 0, 0);
      }
    __builtin_amdgcn_s_setprio(0);

    // softmax (m=0): p = exp2(s*cs); mask only on diagonal/partial tiles
    if (k0 + 63 > qbase) {
#pragma unroll
      for (int nt2 = 0; nt2 < 4; ++nt2) {
        int key = k0 + nt2*16 + lc;
        int qrow = qbase + quad*4;
#pragma unroll
        for (int r = 0; r < 4; ++r) {
          float e = __builtin_amdgcn_exp2f(sc[nt2][r]*cs);
          float p = (key <= qrow + r) ? e : 0.0f;
          rs[r] += p;
          pw[pwb[r] + ((nt2*2 + pcc) ^ pwx[r])*8] = f2b(p);
        }
      }
    } else {
#pragma unroll
      for (int nt2 = 0; nt2 < 4; ++nt2)
#pragma unroll
        for (int r = 0; r < 4; ++r) {
          float p = __builtin_amdgcn_exp2f(sc[nt2][r]*cs);
          rs[r] += p;
          pw[pwb[r] + ((nt2*2 + pcc) ^ pwx[r])*8] = f2b(p);
        }
    }

    // P: C-layout -> A-layout via per-wave LDS roundtrip (intra-wave DS in-order)
    bf16x8 pa[2];
#pragma unroll
    for (int ks = 0; ks < 2; ++ks)
      pa[ks] = ld_bf8(pw + poff[ks]);

    // O += P V
    __builtin_amdgcn_s_setprio(1);
#pragma unroll
    for (int j = 0; j < 8; ++j)
#pragma unroll
      for (int ks = 0; ks < 2; ++ks) {
        bf16x8 vf = ld_bf8(vsb + j*16*64 + voff[ks]);
        o[j] = __builtin_amdgcn_mfma_f32_16x16x32_bf16(pa[ks], vf, o[j], 0, 0, 0);
      }
    __builtin_amdgcn_s_setprio(0);

    // publish prefetched tile: own loads drained, then block-wide sync
    asm volatile("s_waitcnt vmcnt(0)" ::: "memory");
    __builtin_amdgcn_sched_barrier(0);
    __builtin_amdgcn_s_barrier();
    __builtin_amdgcn_sched_barrier(0);
  }

  // epilogue: l-reduce over the 16 key-lanes, normalize, store
#pragma unroll
  for (int r = 0; r < 4; ++r) {
    float v = rs[r];
#pragma unroll
    for (int off2 = 8; off2 >= 1; off2 >>= 1)
      v += __shfl_xor(v, off2);
    float inv = 1.0f / v;
    size_t orow = (size_t)(b*T_SEQ + qbase + quad*4 + r)*EMB + h*HD;
#pragma unroll
    for (int j = 0; j < 8; ++j)
      yb[orow + j*16 + lc] = f2b(o[j][r]*inv);
  }
}

extern "C" void kernel_launch(void* const* d_in, const int* in_sizes, int n_in,
                              void* d_out, int out_size, void* d_ws, size_t ws_size,
                              hipStream_t stream) {
  const float* x      = (const float*)d_in[0];
  const float* W_attn = (const float*)d_in[1];
  const float* b_attn = (const float*)d_in[2];
  const float* W_proj = (const float*)d_in[3];
  const float* fc     = (const float*)d_in[4];
  const float* fs     = (const float*)d_in[5];

  u16* ws   = (u16*)d_ws;
  u16* xb   = ws;                          // 8.39M elems  (later aliased by yb)
  u16* WaT  = xb   + (size_t)MROWS*EMB;    // 6.29M        (later aliased by WpT)
  u16* qkv  = WaT  + (size_t)QKVN*EMB;     // 12.58M
  u16* kbuf = qkv  + (size_t)MROWS*QKVN;   // 2.10M
  u16* vtb  = kbuf + (size_t)MROWS*KVD;    // 2.10M  (vb eliminated)
  u16* WpT  = WaT;   // W_attn^T dead after gemm1
  u16* yb   = xb;    // x_bf16 dead after gemm1
  float* out = (float*)d_out;

  // 1) fused prep: cvt_x + W_attn transpose (independent parts)
  prep_kernel<<<CVT_BLKS + TW1_BLKS, 256, 0, stream>>>(
      (const float4*)x, (ushort4*)xb, W_attn, WaT);
  // 2) gemm1: 256x192 tiles -> 16x16 = 256 blocks (1/CU)
  gemm_kernel<192, 4, 8, 3, 2, 3, 2, 3, true>
      <<<dim3(QKVN/192, MROWS/256), 512, 0, stream>>>(
      xb, WaT, b_attn, qkv, MROWS, QKVN, EMB);
  // 3) fused: rope(K,V)+V-transpose (per-block dataflow) + W_proj transpose
  ropetv_kernel<<<RTV_BLKS + TW2_BX*(EMB/64), 256, 0, stream>>>(
      qkv, fc, fs, kbuf, vtb, W_proj, WpT);
  // 4) flash v7: 1024 blocks (2/CU), 256 threads = 4 waves = 4 heads
  flash_kernel<<<dim3(B_SZ*NKV*(T_SEQ/16)), 256, 0, stream>>>(qkv, kbuf, vtb, yb);
  // 5) gemm2: 256x128 tiles -> 16x16 = 256 blocks (1/CU)
  gemm_kernel<128, 2, 4, 4, 2, 2, 1, 2, false>
      <<<dim3(EMB/128, MROWS/256), 512, 0, stream>>>(
      yb, WpT, nullptr, out, MROWS, EMB, EMB);
}

// Round 9
// 268.618 us; speedup vs baseline: 1.0777x; 1.0379x over previous
//
#include <hip/hip_runtime.h>
#include <cstdint>
#include <cstddef>

#define T_SEQ 2048
#define B_SZ  2
#define EMB   2048
#define NH    16
#define NKV   4
#define HD    128
#define KVD   512
#define QKVN  3072
#define MROWS (B_SZ*T_SEQ)

typedef __bf16 bf16x8 __attribute__((ext_vector_type(8)));
typedef float  f32x4  __attribute__((ext_vector_type(4)));
typedef short  s16x8  __attribute__((ext_vector_type(8)));
typedef unsigned short u16;

__device__ __forceinline__ u16 f2b(float f) {
  uint32_t u = __builtin_bit_cast(uint32_t, f);
  u += 0x7fffu + ((u >> 16) & 1u);      // RNE
  return (u16)(u >> 16);
}
__device__ __forceinline__ float b2f(u16 h) {
  return __builtin_bit_cast(float, (uint32_t)h << 16);
}
__device__ __forceinline__ bf16x8 ld_bf8(const u16* p) {
  return __builtin_bit_cast(bf16x8, *(const s16x8*)p);
}
__device__ __forceinline__ void glds16(const void* g, void* l) {
  __builtin_amdgcn_global_load_lds((const __attribute__((address_space(1))) void*)g,
                                   (__attribute__((address_space(3))) void*)l, 16, 0, 0);
}
template<int N> __device__ __forceinline__ void waitv() {
  if constexpr (N == 0) asm volatile("s_waitcnt vmcnt(0)" ::: "memory");
  else if constexpr (N == 4) asm volatile("s_waitcnt vmcnt(4)" ::: "memory");
  else if constexpr (N == 5) asm volatile("s_waitcnt vmcnt(5)" ::: "memory");
  __builtin_amdgcn_sched_barrier(0);
}

// ---------------- fused prep: fp32->bf16 cvt + W_attn transpose -------------
#define CVT_BLKS (MROWS*EMB/4/256)      // 8192
#define TW1_BX   (QKVN/64)              // 48
#define TW1_BLKS (TW1_BX*(EMB/64))      // 1536
__global__ void prep_kernel(const float4* __restrict__ x, ushort4* __restrict__ xb,
                            const float* __restrict__ Wa, u16* __restrict__ WaT) {
  __shared__ float tile[64][65];
  const int bid = blockIdx.x, tid = threadIdx.x;
  if (bid < CVT_BLKS) {                 // ---- cvt_x part
    int i = bid*256 + tid;
    float4 v = x[i];
    ushort4 o;
    o.x = f2b(v.x); o.y = f2b(v.y); o.z = f2b(v.z); o.w = f2b(v.w);
    xb[i] = o;
    return;
  }
  const int tb = bid - CVT_BLKS;
  const int C = QKVN, R = EMB;
  const int c0 = (tb % TW1_BX)*64, r0 = (tb / TW1_BX)*64;
  const int tx = tid & 15, ty = tid >> 4;
#pragma unroll
  for (int k = 0; k < 4; ++k) {
    int r = ty + k*16;
    float4 v = *(const float4*)&Wa[(size_t)(r0+r)*C + c0 + tx*4];
    tile[r][tx*4+0] = v.x; tile[r][tx*4+1] = v.y;
    tile[r][tx*4+2] = v.z; tile[r][tx*4+3] = v.w;
  }
  __syncthreads();
#pragma unroll
  for (int k = 0; k < 4; ++k) {
    int c = ty + k*16;
    ushort4 o;
    o.x = f2b(tile[tx*4+0][c]);
    o.y = f2b(tile[tx*4+1][c]);
    o.z = f2b(tile[tx*4+2][c]);
    o.w = f2b(tile[tx*4+3][c]);
    *(ushort4*)&WaT[(size_t)(c0+c)*R + r0 + tx*4] = o;
  }
}

// ---------------- bf16 GEMM, 256xBN tile, 2-phase/K-tile schedule -----------
// C(MxN) = A(MxK)*Bt(NxK)^T (+bias). 512 thr = 8 waves (2 M-rows x 4 N-cols),
// per-wave 128 x NF*16. Was 4 phases of 8-12 MFMA (r2): barrier+drain overhead
// per phase dominated (MfmaUtil ~25%). Now 2 phases/K-tile at reference (m201)
// granularity: P-odd reads af rows 0-63 of each wave band + ALL bfv (B held in
// REGISTERS across the pair -> B LDS frees after P-odd); P-even reads af rows
// 64-127. MFMA/phase: 24 (gemm1, NF=3) / 16 (gemm2, NF=2) = 48/32 per SIMD.
// A-row-half h occupies 64-row blocks {h, h+2} (wave bands at 0,128).
// Ledger (per 2-tile iter, buf0=t, buf1=t+1):
//   stages  P1:{Ah1(t+1)->a1}  P2:{B(t+2)->b0, Ah0(t+2)->a0}
//           P3:{Ah1(t+2)->a0}  P4:{B(t+3)->b1, Ah0(t+3)->a1}
//   each stage is issued after the barrier that frees its region (a0h0 free
//   after P1, a0h1 after P2, b0 after P1(regs), a1h0 after P3, a1h1 after P4,
//   b1 after P3). Reads are >=2 phases after their stage. vmcnt(SB+2) at
//   P2/P4-end leaves exactly that phase's own stages in flight; never 0 in
//   the main loop. Prologue leaves {Ah0(1),B(1)}; epilogue drains once.
template<int BN, int NF, int SB, int VMC, bool BF16_OUT>
__global__ __launch_bounds__(512, 2) void gemm_kernel(const u16* __restrict__ A,
        const u16* __restrict__ Bt, const float* __restrict__ bias,
        void* __restrict__ Cout, int M, int N, int K) {
  __shared__ u16 As[2][256*64];
  __shared__ u16 Bs[2][BN*64];
  const int tid = threadIdx.x;
  const int w = tid >> 6, lane = tid & 63;
  const int quad = lane >> 4, lc = lane & 15;
  const int wrow = w >> 2, wcol = w & 3;   // 2 x 4 waves, per-wave 128 x NF*16
  const int gx = gridDim.x;
  const int lin = blockIdx.y*gx + blockIdx.x;
  const int swz = (lin & 7)*32 + (lin >> 3);  // 256 blocks, 32/XCD
  const int m0 = (swz / gx)*256, n0 = (swz % gx)*BN;

  f32x4 acc[8][NF] = {};
  bf16x8 af[4][2], bfv[NF][2];

  int xoff[2];
#pragma unroll
  for (int ks = 0; ks < 2; ++ks) xoff[ks] = ((ks*4 + quad) ^ (lc & 7))*8;
  const int arow0 = (wrow*128 + lc)*64;
  const int brow0 = (wcol*NF*16 + lc)*64;

  const int srb  = tid >> 3;
  const int spos = (tid & 7) ^ (srb & 7);
  const u16* sAp = A  + (size_t)(m0 + srb)*K + spos*8;
  const u16* sBp = Bt + (size_t)(n0 + srb)*K + spos*8;

// stage A row-half h of tile t: 64-row blocks {h, h+2}
#define STAGE_AH(bf_, t_, h_) do { \
    glds16(sAp + (size_t)(h_)*64*K     + (size_t)(t_)*64, &As[bf_][(h_)*4096 + w*512]); \
    glds16(sAp + (size_t)((h_)+2)*64*K + (size_t)(t_)*64, &As[bf_][((h_)+2)*4096 + w*512]); \
  } while (0)
#define STAGE_B(bf_, t_) do { \
    _Pragma("unroll") for (int r = 0; r < SB; ++r) \
      glds16(sBp + (size_t)r*64*K + (size_t)(t_)*64, &Bs[bf_][r*4096 + w*512]); \
  } while (0)
// read af rows of half h (band row h*64 + i*16)
#define LDAH(S_, h_) do { _Pragma("unroll") for (int i = 0; i < 4; ++i) { \
    af[i][0] = ld_bf8((S_) + arow0 + (h_)*4096 + i*1024 + xoff[0]); \
    af[i][1] = ld_bf8((S_) + arow0 + (h_)*4096 + i*1024 + xoff[1]); } } while (0)
#define LDBALL(S_) do { _Pragma("unroll") for (int j = 0; j < NF; ++j) { \
    bfv[j][0] = ld_bf8((S_) + brow0 + j*1024 + xoff[0]); \
    bfv[j][1] = ld_bf8((S_) + brow0 + j*1024 + xoff[1]); } } while (0)
#define CLH(h_) do { _Pragma("unroll") for (int ks = 0; ks < 2; ++ks) \
    _Pragma("unroll") for (int i = 0; i < 4; ++i) \
    _Pragma("unroll") for (int j = 0; j < NF; ++j) \
      acc[(h_)*4+i][j] = __builtin_amdgcn_mfma_f32_16x16x32_bf16( \
          af[i][ks], bfv[j][ks], acc[(h_)*4+i][j], 0, 0, 0); } while (0)
#define BARX()  __builtin_amdgcn_s_barrier()
#define SCHB()  __builtin_amdgcn_sched_barrier(0)
#define MFMAPH(h_) do { BARX(); \
    asm volatile("s_waitcnt lgkmcnt(0)" ::: "memory"); SCHB(); \
    __builtin_amdgcn_s_setprio(1); CLH(h_); __builtin_amdgcn_s_setprio(0); \
  } while (0)

  const int NT = K >> 6;   // even, >= 4
  // prologue: A(0) both halves + B(0) drained; Ah0(1)+B(1) left in flight
  STAGE_AH(0, 0, 0); STAGE_AH(0, 0, 1); STAGE_B(0, 0);
  STAGE_AH(1, 1, 0); STAGE_B(1, 1);
  waitv<VMC>();
  BARX(); SCHB();

  for (int t0 = 0; t0 < NT-2; t0 += 2) {
    const u16 *a0 = As[0], *b0 = Bs[0], *a1 = As[1], *b1 = Bs[1];
    // P1: tile t0 half 0 (+ all B of t0 into regs)
    LDAH(a0, 0); LDBALL(b0); STAGE_AH(1, t0+1, 1);
    MFMAPH(0); BARX();
    // P2: tile t0 half 1
    LDAH(a0, 1); STAGE_B(0, t0+2); STAGE_AH(0, t0+2, 0);
    MFMAPH(1);
    waitv<VMC>();
    BARX(); SCHB();
    // P3: tile t0+1 half 0
    LDAH(a1, 0); LDBALL(b1); STAGE_AH(0, t0+2, 1);
    MFMAPH(0); BARX();
    // P4: tile t0+1 half 1
    LDAH(a1, 1); STAGE_B(1, t0+3); STAGE_AH(1, t0+3, 0);
    MFMAPH(1);
    waitv<VMC>();
    BARX(); SCHB();
  }
  // epilogue: tiles NT-2 (buf0), NT-1 (buf1); only Ah1(NT-1) left to stage
  {
    const u16 *a0 = As[0], *b0 = Bs[0], *a1 = As[1], *b1 = Bs[1];
    LDAH(a0, 0); LDBALL(b0); STAGE_AH(1, NT-1, 1);
    MFMAPH(0); BARX();
    LDAH(a0, 1);
    MFMAPH(1);
    waitv<0>();
    BARX(); SCHB();
    LDAH(a1, 0); LDBALL(b1);
    MFMAPH(0); BARX();
    LDAH(a1, 1);
    MFMAPH(1);
  }

#undef STAGE_AH
#undef STAGE_B
#undef LDAH
#undef LDBALL
#undef CLH
#undef BARX
#undef SCHB
#undef MFMAPH

  // epilogue C-write
#pragma unroll
  for (int j = 0; j < NF; ++j) {
    int col = n0 + wcol*NF*16 + j*16 + lc;
    float bv = BF16_OUT ? bias[col] : 0.0f;
#pragma unroll
    for (int i = 0; i < 8; ++i) {
      int rowb = m0 + wrow*128 + i*16 + quad*4;
#pragma unroll
      for (int r = 0; r < 4; ++r) {
        float v = acc[i][j][r] + bv;
        if (BF16_OUT) ((u16*)Cout)[(size_t)(rowb+r)*N + col] = f2b(v);
        else          ((float*)Cout)[(size_t)(rowb+r)*N + col] = v;
      }
    }
  }
}

// ---------------- fused: RoPE(K,V) + V-transpose + W_proj transpose ---------
#define RTV_BLKS (8*(T_SEQ/32))         // 512
#define TW2_BX   (EMB/64)               // 32
__global__ void ropetv_kernel(const u16* __restrict__ qkv, const float* __restrict__ fc,
                              const float* __restrict__ fs, u16* __restrict__ kout,
                              u16* __restrict__ vtb, const float* __restrict__ Wp,
                              u16* __restrict__ WpT) {
  __shared__ float tile[64][65];        // tw2 part
  __shared__ u16 vt[32][136];           // rtv part: [t][d], row stride 272B
  const int bid = blockIdx.x, tid = threadIdx.x;
  if (bid < RTV_BLKS) {
    const int bkv = bid & 7;
    const int t0 = (bid >> 3)*32;
    const int b = bkv >> 2, kv = bkv & 3;
    const int tl = tid >> 3, ch = tid & 7;
    const int t = t0 + tl;
    const int row = b*T_SEQ + t;
    const u16* p = qkv + (size_t)row*QKVN + EMB + kv*HD + ch*16;
    s16x8 kin0 = *(const s16x8*)p,        kin1 = *(const s16x8*)(p + 8);
    s16x8 vin0 = *(const s16x8*)(p + KVD), vin1 = *(const s16x8*)(p + KVD + 8);
    s16x8 ko0, ko1, vo0, vo1;
#pragma unroll
    for (int j = 0; j < 4; ++j) {
      int i = ch*8 + j;
      float c = fc[t*64 + i], s = fs[t*64 + i];
      float ka = b2f((u16)kin0[2*j]), kb2 = b2f((u16)kin0[2*j+1]);
      float va = b2f((u16)vin0[2*j]), vb2 = b2f((u16)vin0[2*j+1]);
      ko0[2*j]   = (short)f2b(ka*c - kb2*s);
      ko0[2*j+1] = (short)f2b(ka*s + kb2*c);
      vo0[2*j]   = (short)f2b(va*c - vb2*s);
      vo0[2*j+1] = (short)f2b(va*s + vb2*c);
    }
#pragma unroll
    for (int j = 0; j < 4; ++j) {
      int i = ch*8 + 4 + j;
      float c = fc[t*64 + i], s = fs[t*64 + i];
      float ka = b2f((u16)kin1[2*j]), kb2 = b2f((u16)kin1[2*j+1]);
      float va = b2f((u16)vin1[2*j]), vb2 = b2f((u16)vin1[2*j+1]);
      ko1[2*j]   = (short)f2b(ka*c - kb2*s);
      ko1[2*j+1] = (short)f2b(ka*s + kb2*c);
      vo1[2*j]   = (short)f2b(va*c - vb2*s);
      vo1[2*j+1] = (short)f2b(va*s + vb2*c);
    }
    u16* kq = kout + (size_t)row*KVD + kv*HD + ch*16;
    *(s16x8*)kq       = ko0;
    *(s16x8*)(kq + 8) = ko1;
    *(s16x8*)&vt[tl][ch*16]     = vo0;
    *(s16x8*)&vt[tl][ch*16 + 8] = vo1;
    __syncthreads();
    const int d = tid >> 1, hf = tid & 1;
    u16 ov[16];
#pragma unroll
    for (int e = 0; e < 16; ++e) ov[e] = vt[hf*16 + e][d];
    u16* vq = vtb + (size_t)(bkv*HD + d)*T_SEQ + t0 + hf*16;
    *(s16x8*)vq       = *(s16x8*)&ov[0];
    *(s16x8*)(vq + 8) = *(s16x8*)&ov[8];
    return;
  }
  const int tb = bid - RTV_BLKS;
  const int C = EMB, R = EMB;
  const int c0 = (tb % TW2_BX)*64, r0 = (tb / TW2_BX)*64;
  const int tx = tid & 15, ty = tid >> 4;
#pragma unroll
  for (int k = 0; k < 4; ++k) {
    int r = ty + k*16;
    float4 v = *(const float4*)&Wp[(size_t)(r0+r)*C + c0 + tx*4];
    tile[r][tx*4+0] = v.x; tile[r][tx*4+1] = v.y;
    tile[r][tx*4+2] = v.z; tile[r][tx*4+3] = v.w;
  }
  __syncthreads();
#pragma unroll
  for (int k = 0; k < 4; ++k) {
    int c = ty + k*16;
    ushort4 o;
    o.x = f2b(tile[tx*4+0][c]);
    o.y = f2b(tile[tx*4+1][c]);
    o.z = f2b(tile[tx*4+2][c]);
    o.w = f2b(tile[tx*4+3][c]);
    *(ushort4*)&WpT[(size_t)(c0+c)*R + r0 + tx*4] = o;
  }
}

// ---------------- flash attention v7 (best measured; unchanged from r8) -----
__global__ __launch_bounds__(256, 2) void flash_kernel(const u16* __restrict__ qkv,
    const u16* __restrict__ kb, const u16* __restrict__ vtb, u16* __restrict__ yb) {
  __shared__ u16 Ks[2][64*128];          // 2 x 16 KB
  __shared__ u16 Vs[2][128*64];          // 2 x 16 KB
  __shared__ u16 Ps[4][16*64];           // 4 x 2 KB (chunk-XOR swizzled)
  const int tid = threadIdx.x;
  const int w = tid >> 6, lane = tid & 63;
  const int quad = lane >> 4, lc = lane & 15;
  const int bkv = blockIdx.x & 7;        // XCD-pinned (b,kv)
  const int r_  = blockIdx.x >> 3;       // 0..127
  const int b = bkv >> 2, kv = bkv & 3;
  const int h = kv*4 + w;                // wave = one head of the group
  const int qbase = (127 - r_)*16;       // heavy q-tiles dispatch first

  bf16x8 qf[4];
  {
    const u16* qp = qkv + (size_t)(b*T_SEQ + qbase + lc)*QKVN + h*HD + quad*8;
#pragma unroll
    for (int ks = 0; ks < 4; ++ks) qf[ks] = ld_bf8(qp + ks*32);
  }

  f32x4 o[8] = {};
  float rs[4] = {0.f, 0.f, 0.f, 0.f};
  const u16* kbase = kb  + (size_t)b*T_SEQ*KVD + kv*HD;
  const u16* vbase = vtb + (size_t)bkv*HD*T_SEQ;
  const int nk = qbase + 16;
  const int nt = (nk + 63) >> 6;
  const float cs = 0.08838834764831845f * 1.4426950408889634f;  // scale * log2(e)
  u16* pw = Ps[w];

  const u16* kptr[4];
  const u16* vptr[4];
#pragma unroll
  for (int rr = 0; rr < 4; ++rr) {
    int krow = (rr*4 + w)*4 + (lane >> 4);
    int kcc  = (lane & 15) ^ (krow & 15);
    kptr[rr] = kbase + (size_t)krow*KVD + kcc*8;
    int vrow = (rr*4 + w)*8 + (lane >> 3);
    int vcc  = (lane & 7) ^ (vrow & 7);
    vptr[rr] = vbase + (size_t)vrow*T_SEQ + vcc*8;
  }

  int koff[4], voff[2], poff[2];
#pragma unroll
  for (int ks = 0; ks < 4; ++ks) koff[ks] = lc*128 + (((ks*4 + quad) ^ lc)*8);
#pragma unroll
  for (int ks = 0; ks < 2; ++ks) voff[ks] = lc*64 + (((ks*4 + quad) ^ (lc & 7))*8);
#pragma unroll
  for (int ks = 0; ks < 2; ++ks) poff[ks] = lc*64 + (((ks*4 + quad) ^ (lc & 7))*8);
  int pwb[4], pwx[4];
#pragma unroll
  for (int r = 0; r < 4; ++r) {
    pwb[r] = (quad*4 + r)*64 + (lc & 7);
    pwx[r] = (quad*4 + r) & 7;
  }
  const int pcc = lc >> 3;

#pragma unroll
  for (int rr = 0; rr < 4; ++rr) glds16(kptr[rr], &Ks[0][(rr*4 + w)*512]);
#pragma unroll
  for (int rr = 0; rr < 4; ++rr) glds16(vptr[rr], &Vs[0][(rr*4 + w)*512]);
  asm volatile("s_waitcnt vmcnt(0)" ::: "memory");
  __builtin_amdgcn_sched_barrier(0);
  __builtin_amdgcn_s_barrier();
  __builtin_amdgcn_sched_barrier(0);

  for (int t = 0; t < nt; ++t) {
    const int cur = t & 1;
    if (t + 1 < nt) {
#pragma unroll
      for (int rr = 0; rr < 4; ++rr)
        glds16(kptr[rr] + (size_t)(t+1)*64*KVD, &Ks[cur^1][(rr*4 + w)*512]);
#pragma unroll
      for (int rr = 0; rr < 4; ++rr)
        glds16(vptr[rr] + (size_t)(t+1)*64,     &Vs[cur^1][(rr*4 + w)*512]);
    }
    const u16* ksb = Ks[cur];
    const u16* vsb = Vs[cur];
    const int k0 = t*64;

    f32x4 sc[4] = {};
    __builtin_amdgcn_s_setprio(1);
#pragma unroll
    for (int nt2 = 0; nt2 < 4; ++nt2)
#pragma unroll
      for (int ks = 0; ks < 4; ++ks) {
        bf16x8 kf = ld_bf8(ksb + nt2*16*128 + koff[ks]);
        sc[nt2] = __builtin_amdgcn_mfma_f32_16x16x32_bf16(qf[ks], kf, sc[nt2], 0, 0, 0);
      }
    __builtin_amdgcn_s_setprio(0);

    if (k0 + 63 > qbase) {
#pragma unroll
      for (int nt2 = 0; nt2 < 4; ++nt2) {
        int key = k0 + nt2*16 + lc;
        int qrow = qbase + quad*4;
#pragma unroll
        for (int r = 0; r < 4; ++r) {
          float e = __builtin_amdgcn_exp2f(sc[nt2][r]*cs);
          float p = (key <= qrow + r) ? e : 0.0f;
          rs[r] += p;
          pw[pwb[r] + ((nt2*2 + pcc) ^ pwx[r])*8] = f2b(p);
        }
      }
    } else {
#pragma unroll
      for (int nt2 = 0; nt2 < 4; ++nt2)
#pragma unroll
        for (int r = 0; r < 4; ++r) {
          float p = __builtin_amdgcn_exp2f(sc[nt2][r]*cs);
          rs[r] += p;
          pw[pwb[r] + ((nt2*2 + pcc) ^ pwx[r])*8] = f2b(p);
        }
    }

    bf16x8 pa[2];
#pragma unroll
    for (int ks = 0; ks < 2; ++ks)
      pa[ks] = ld_bf8(pw + poff[ks]);

    __builtin_amdgcn_s_setprio(1);
#pragma unroll
    for (int j = 0; j < 8; ++j)
#pragma unroll
      for (int ks = 0; ks < 2; ++ks) {
        bf16x8 vf = ld_bf8(vsb + j*16*64 + voff[ks]);
        o[j] = __builtin_amdgcn_mfma_f32_16x16x32_bf16(pa[ks], vf, o[j], 0, 0, 0);
      }
    __builtin_amdgcn_s_setprio(0);

    asm volatile("s_waitcnt vmcnt(0)" ::: "memory");
    __builtin_amdgcn_sched_barrier(0);
    __builtin_amdgcn_s_barrier();
    __builtin_amdgcn_sched_barrier(0);
  }

#pragma unroll
  for (int r = 0; r < 4; ++r) {
    float v = rs[r];
#pragma unroll
    for (int off2 = 8; off2 >= 1; off2 >>= 1)
      v += __shfl_xor(v, off2);
    float inv = 1.0f / v;
    size_t orow = (size_t)(b*T_SEQ + qbase + quad*4 + r)*EMB + h*HD;
#pragma unroll
    for (int j = 0; j < 8; ++j)
      yb[orow + j*16 + lc] = f2b(o[j][r]*inv);
  }
}

extern "C" void kernel_launch(void* const* d_in, const int* in_sizes, int n_in,
                              void* d_out, int out_size, void* d_ws, size_t ws_size,
                              hipStream_t stream) {
  const float* x      = (const float*)d_in[0];
  const float* W_attn = (const float*)d_in[1];
  const float* b_attn = (const float*)d_in[2];
  const float* W_proj = (const float*)d_in[3];
  const float* fc     = (const float*)d_in[4];
  const float* fs     = (const float*)d_in[5];

  u16* ws   = (u16*)d_ws;
  u16* xb   = ws;                          // 8.39M elems  (later aliased by yb)
  u16* WaT  = xb   + (size_t)MROWS*EMB;    // 6.29M        (later aliased by WpT)
  u16* qkv  = WaT  + (size_t)QKVN*EMB;     // 12.58M
  u16* kbuf = qkv  + (size_t)MROWS*QKVN;   // 2.10M
  u16* vtb  = kbuf + (size_t)MROWS*KVD;    // 2.10M
  u16* WpT  = WaT;   // W_attn^T dead after gemm1
  u16* yb   = xb;    // x_bf16 dead after gemm1
  float* out = (float*)d_out;

  // 1) fused prep: cvt_x + W_attn transpose
  prep_kernel<<<CVT_BLKS + TW1_BLKS, 256, 0, stream>>>(
      (const float4*)x, (ushort4*)xb, W_attn, WaT);
  // 2) gemm1: 256x192 tiles -> 256 blocks; 2-phase, NF=3, SB=3, vmcnt(5)
  gemm_kernel<192, 3, 3, 5, true>
      <<<dim3(QKVN/192, MROWS/256), 512, 0, stream>>>(
      xb, WaT, b_attn, qkv, MROWS, QKVN, EMB);
  // 3) fused: rope(K,V)+V-transpose + W_proj transpose
  ropetv_kernel<<<RTV_BLKS + TW2_BX*(EMB/64), 256, 0, stream>>>(
      qkv, fc, fs, kbuf, vtb, W_proj, WpT);
  // 4) flash v7
  flash_kernel<<<dim3(B_SZ*NKV*(T_SEQ/16)), 256, 0, stream>>>(qkv, kbuf, vtb, yb);
  // 5) gemm2: 256x128 tiles -> 256 blocks; 2-phase, NF=2, SB=2, vmcnt(4)
  gemm_kernel<128, 2, 2, 4, false>
      <<<dim3(EMB/128, MROWS/256), 512, 0, stream>>>(
      yb, WpT, nullptr, out, MROWS, EMB, EMB);
}

// Round 10
// 267.908 us; speedup vs baseline: 1.0805x; 1.0026x over previous
//
#include <hip/hip_runtime.h>
#include <cstdint>
#include <cstddef>

#define T_SEQ 2048
#define B_SZ  2
#define EMB   2048
#define NH    16
#define NKV   4
#define HD    128
#define KVD   512
#define QKVN  3072
#define MROWS (B_SZ*T_SEQ)

typedef __bf16 bf16x8 __attribute__((ext_vector_type(8)));
typedef float  f32x4  __attribute__((ext_vector_type(4)));
typedef short  s16x8  __attribute__((ext_vector_type(8)));
typedef unsigned short u16;

__device__ __forceinline__ u16 f2b(float f) {
  uint32_t u = __builtin_bit_cast(uint32_t, f);
  u += 0x7fffu + ((u >> 16) & 1u);      // RNE
  return (u16)(u >> 16);
}
__device__ __forceinline__ float b2f(u16 h) {
  return __builtin_bit_cast(float, (uint32_t)h << 16);
}
__device__ __forceinline__ bf16x8 ld_bf8(const u16* p) {
  return __builtin_bit_cast(bf16x8, *(const s16x8*)p);
}
__device__ __forceinline__ void glds16(const void* g, void* l) {
  __builtin_amdgcn_global_load_lds((const __attribute__((address_space(1))) void*)g,
                                   (__attribute__((address_space(3))) void*)l, 16, 0, 0);
}
template<int N> __device__ __forceinline__ void waitv() {
  if constexpr (N == 0) asm volatile("s_waitcnt vmcnt(0)" ::: "memory");
  else if constexpr (N == 4) asm volatile("s_waitcnt vmcnt(4)" ::: "memory");
  else if constexpr (N == 5) asm volatile("s_waitcnt vmcnt(5)" ::: "memory");
  __builtin_amdgcn_sched_barrier(0);
}

// ---------------- fused prep: fp32->bf16 cvt + W_attn transpose -------------
#define CVT_BLKS (MROWS*EMB/4/256)      // 8192
#define TW1_BX   (QKVN/64)              // 48
#define TW1_BLKS (TW1_BX*(EMB/64))      // 1536
__global__ void prep_kernel(const float4* __restrict__ x, ushort4* __restrict__ xb,
                            const float* __restrict__ Wa, u16* __restrict__ WaT) {
  __shared__ float tile[64][65];
  const int bid = blockIdx.x, tid = threadIdx.x;
  if (bid < CVT_BLKS) {                 // ---- cvt_x part
    int i = bid*256 + tid;
    float4 v = x[i];
    ushort4 o;
    o.x = f2b(v.x); o.y = f2b(v.y); o.z = f2b(v.z); o.w = f2b(v.w);
    xb[i] = o;
    return;
  }
  const int tb = bid - CVT_BLKS;
  const int C = QKVN, R = EMB;
  const int c0 = (tb % TW1_BX)*64, r0 = (tb / TW1_BX)*64;
  const int tx = tid & 15, ty = tid >> 4;
#pragma unroll
  for (int k = 0; k < 4; ++k) {
    int r = ty + k*16;
    float4 v = *(const float4*)&Wa[(size_t)(r0+r)*C + c0 + tx*4];
    tile[r][tx*4+0] = v.x; tile[r][tx*4+1] = v.y;
    tile[r][tx*4+2] = v.z; tile[r][tx*4+3] = v.w;
  }
  __syncthreads();
#pragma unroll
  for (int k = 0; k < 4; ++k) {
    int c = ty + k*16;
    ushort4 o;
    o.x = f2b(tile[tx*4+0][c]);
    o.y = f2b(tile[tx*4+1][c]);
    o.z = f2b(tile[tx*4+2][c]);
    o.w = f2b(tile[tx*4+3][c]);
    *(ushort4*)&WaT[(size_t)(c0+c)*R + r0 + tx*4] = o;
  }
}

// ---------------- bf16 GEMM, 256xBN tile, 2-phase/K-tile schedule -----------
// (unchanged from r9 — verified: -10us vs r8's 4-phase)
template<int BN, int NF, int SB, int VMC, bool BF16_OUT>
__global__ __launch_bounds__(512, 2) void gemm_kernel(const u16* __restrict__ A,
        const u16* __restrict__ Bt, const float* __restrict__ bias,
        void* __restrict__ Cout, int M, int N, int K) {
  __shared__ u16 As[2][256*64];
  __shared__ u16 Bs[2][BN*64];
  const int tid = threadIdx.x;
  const int w = tid >> 6, lane = tid & 63;
  const int quad = lane >> 4, lc = lane & 15;
  const int wrow = w >> 2, wcol = w & 3;   // 2 x 4 waves, per-wave 128 x NF*16
  const int gx = gridDim.x;
  const int lin = blockIdx.y*gx + blockIdx.x;
  const int swz = (lin & 7)*32 + (lin >> 3);  // 256 blocks, 32/XCD
  const int m0 = (swz / gx)*256, n0 = (swz % gx)*BN;

  f32x4 acc[8][NF] = {};
  bf16x8 af[4][2], bfv[NF][2];

  int xoff[2];
#pragma unroll
  for (int ks = 0; ks < 2; ++ks) xoff[ks] = ((ks*4 + quad) ^ (lc & 7))*8;
  const int arow0 = (wrow*128 + lc)*64;
  const int brow0 = (wcol*NF*16 + lc)*64;

  const int srb  = tid >> 3;
  const int spos = (tid & 7) ^ (srb & 7);
  const u16* sAp = A  + (size_t)(m0 + srb)*K + spos*8;
  const u16* sBp = Bt + (size_t)(n0 + srb)*K + spos*8;

#define STAGE_AH(bf_, t_, h_) do { \
    glds16(sAp + (size_t)(h_)*64*K     + (size_t)(t_)*64, &As[bf_][(h_)*4096 + w*512]); \
    glds16(sAp + (size_t)((h_)+2)*64*K + (size_t)(t_)*64, &As[bf_][((h_)+2)*4096 + w*512]); \
  } while (0)
#define STAGE_B(bf_, t_) do { \
    _Pragma("unroll") for (int r = 0; r < SB; ++r) \
      glds16(sBp + (size_t)r*64*K + (size_t)(t_)*64, &Bs[bf_][r*4096 + w*512]); \
  } while (0)
#define LDAH(S_, h_) do { _Pragma("unroll") for (int i = 0; i < 4; ++i) { \
    af[i][0] = ld_bf8((S_) + arow0 + (h_)*4096 + i*1024 + xoff[0]); \
    af[i][1] = ld_bf8((S_) + arow0 + (h_)*4096 + i*1024 + xoff[1]); } } while (0)
#define LDBALL(S_) do { _Pragma("unroll") for (int j = 0; j < NF; ++j) { \
    bfv[j][0] = ld_bf8((S_) + brow0 + j*1024 + xoff[0]); \
    bfv[j][1] = ld_bf8((S_) + brow0 + j*1024 + xoff[1]); } } while (0)
#define CLH(h_) do { _Pragma("unroll") for (int ks = 0; ks < 2; ++ks) \
    _Pragma("unroll") for (int i = 0; i < 4; ++i) \
    _Pragma("unroll") for (int j = 0; j < NF; ++j) \
      acc[(h_)*4+i][j] = __builtin_amdgcn_mfma_f32_16x16x32_bf16( \
          af[i][ks], bfv[j][ks], acc[(h_)*4+i][j], 0, 0, 0); } while (0)
#define BARX()  __builtin_amdgcn_s_barrier()
#define SCHB()  __builtin_amdgcn_sched_barrier(0)
#define MFMAPH(h_) do { BARX(); \
    asm volatile("s_waitcnt lgkmcnt(0)" ::: "memory"); SCHB(); \
    __builtin_amdgcn_s_setprio(1); CLH(h_); __builtin_amdgcn_s_setprio(0); \
  } while (0)

  const int NT = K >> 6;   // even, >= 4
  STAGE_AH(0, 0, 0); STAGE_AH(0, 0, 1); STAGE_B(0, 0);
  STAGE_AH(1, 1, 0); STAGE_B(1, 1);
  waitv<VMC>();
  BARX(); SCHB();

  for (int t0 = 0; t0 < NT-2; t0 += 2) {
    const u16 *a0 = As[0], *b0 = Bs[0], *a1 = As[1], *b1 = Bs[1];
    LDAH(a0, 0); LDBALL(b0); STAGE_AH(1, t0+1, 1);
    MFMAPH(0); BARX();
    LDAH(a0, 1); STAGE_B(0, t0+2); STAGE_AH(0, t0+2, 0);
    MFMAPH(1);
    waitv<VMC>();
    BARX(); SCHB();
    LDAH(a1, 0); LDBALL(b1); STAGE_AH(0, t0+2, 1);
    MFMAPH(0); BARX();
    LDAH(a1, 1); STAGE_B(1, t0+3); STAGE_AH(1, t0+3, 0);
    MFMAPH(1);
    waitv<VMC>();
    BARX(); SCHB();
  }
  {
    const u16 *a0 = As[0], *b0 = Bs[0], *a1 = As[1], *b1 = Bs[1];
    LDAH(a0, 0); LDBALL(b0); STAGE_AH(1, NT-1, 1);
    MFMAPH(0); BARX();
    LDAH(a0, 1);
    MFMAPH(1);
    waitv<0>();
    BARX(); SCHB();
    LDAH(a1, 0); LDBALL(b1);
    MFMAPH(0); BARX();
    LDAH(a1, 1);
    MFMAPH(1);
  }

#undef STAGE_AH
#undef STAGE_B
#undef LDAH
#undef LDBALL
#undef CLH
#undef BARX
#undef SCHB
#undef MFMAPH

#pragma unroll
  for (int j = 0; j < NF; ++j) {
    int col = n0 + wcol*NF*16 + j*16 + lc;
    float bv = BF16_OUT ? bias[col] : 0.0f;
#pragma unroll
    for (int i = 0; i < 8; ++i) {
      int rowb = m0 + wrow*128 + i*16 + quad*4;
#pragma unroll
      for (int r = 0; r < 4; ++r) {
        float v = acc[i][j][r] + bv;
        if (BF16_OUT) ((u16*)Cout)[(size_t)(rowb+r)*N + col] = f2b(v);
        else          ((float*)Cout)[(size_t)(rowb+r)*N + col] = v;
      }
    }
  }
}

// ---------------- fused: RoPE(K,V) + V-transpose + W_proj transpose ---------
#define RTV_BLKS (8*(T_SEQ/32))         // 512
#define TW2_BX   (EMB/64)               // 32
__global__ void ropetv_kernel(const u16* __restrict__ qkv, const float* __restrict__ fc,
                              const float* __restrict__ fs, u16* __restrict__ kout,
                              u16* __restrict__ vtb, const float* __restrict__ Wp,
                              u16* __restrict__ WpT) {
  __shared__ float tile[64][65];        // tw2 part
  __shared__ u16 vt[32][136];           // rtv part: [t][d], row stride 272B
  const int bid = blockIdx.x, tid = threadIdx.x;
  if (bid < RTV_BLKS) {
    const int bkv = bid & 7;
    const int t0 = (bid >> 3)*32;
    const int b = bkv >> 2, kv = bkv & 3;
    const int tl = tid >> 3, ch = tid & 7;
    const int t = t0 + tl;
    const int row = b*T_SEQ + t;
    const u16* p = qkv + (size_t)row*QKVN + EMB + kv*HD + ch*16;
    s16x8 kin0 = *(const s16x8*)p,        kin1 = *(const s16x8*)(p + 8);
    s16x8 vin0 = *(const s16x8*)(p + KVD), vin1 = *(const s16x8*)(p + KVD + 8);
    s16x8 ko0, ko1, vo0, vo1;
#pragma unroll
    for (int j = 0; j < 4; ++j) {
      int i = ch*8 + j;
      float c = fc[t*64 + i], s = fs[t*64 + i];
      float ka = b2f((u16)kin0[2*j]), kb2 = b2f((u16)kin0[2*j+1]);
      float va = b2f((u16)vin0[2*j]), vb2 = b2f((u16)vin0[2*j+1]);
      ko0[2*j]   = (short)f2b(ka*c - kb2*s);
      ko0[2*j+1] = (short)f2b(ka*s + kb2*c);
      vo0[2*j]   = (short)f2b(va*c - vb2*s);
      vo0[2*j+1] = (short)f2b(va*s + vb2*c);
    }
#pragma unroll
    for (int j = 0; j < 4; ++j) {
      int i = ch*8 + 4 + j;
      float c = fc[t*64 + i], s = fs[t*64 + i];
      float ka = b2f((u16)kin1[2*j]), kb2 = b2f((u16)kin1[2*j+1]);
      float va = b2f((u16)vin1[2*j]), vb2 = b2f((u16)vin1[2*j+1]);
      ko1[2*j]   = (short)f2b(ka*c - kb2*s);
      ko1[2*j+1] = (short)f2b(ka*s + kb2*c);
      vo1[2*j]   = (short)f2b(va*c - vb2*s);
      vo1[2*j+1] = (short)f2b(va*s + vb2*c);
    }
    u16* kq = kout + (size_t)row*KVD + kv*HD + ch*16;
    *(s16x8*)kq       = ko0;
    *(s16x8*)(kq + 8) = ko1;
    *(s16x8*)&vt[tl][ch*16]     = vo0;
    *(s16x8*)&vt[tl][ch*16 + 8] = vo1;
    __syncthreads();
    const int d = tid >> 1, hf = tid & 1;
    u16 ov[16];
#pragma unroll
    for (int e = 0; e < 16; ++e) ov[e] = vt[hf*16 + e][d];
    u16* vq = vtb + (size_t)(bkv*HD + d)*T_SEQ + t0 + hf*16;
    *(s16x8*)vq       = *(s16x8*)&ov[0];
    *(s16x8*)(vq + 8) = *(s16x8*)&ov[8];
    return;
  }
  const int tb = bid - RTV_BLKS;
  const int C = EMB, R = EMB;
  const int c0 = (tb % TW2_BX)*64, r0 = (tb / TW2_BX)*64;
  const int tx = tid & 15, ty = tid >> 4;
#pragma unroll
  for (int k = 0; k < 4; ++k) {
    int r = ty + k*16;
    float4 v = *(const float4*)&Wp[(size_t)(r0+r)*C + c0 + tx*4];
    tile[r][tx*4+0] = v.x; tile[r][tx*4+1] = v.y;
    tile[r][tx*4+2] = v.z; tile[r][tx*4+3] = v.w;
  }
  __syncthreads();
#pragma unroll
  for (int k = 0; k < 4; ++k) {
    int c = ty + k*16;
    ushort4 o;
    o.x = f2b(tile[tx*4+0][c]);
    o.y = f2b(tile[tx*4+1][c]);
    o.z = f2b(tile[tx*4+2][c]);
    o.w = f2b(tile[tx*4+3][c]);
    *(ushort4*)&WpT[(size_t)(c0+c)*R + r0 + tx*4] = o;
  }
}

// ---------------- flash attention v10: swapped QK^T, packed b64 P-writes ----
// v7 structure (best measured) with ONE local change: compute mfma(K,Q) so the
// score layout is row=key, col=q -> each lane holds P[k=16nt2+4quad+r][q=lc],
// i.e. 4 k-ADJACENT values per nt2 -> pack ushort4, write 4 ds_write_b64/tile
// (was 16 scalar ds_write_b16, ~93 of the ~500 LDS-pipe cyc/wave/tile).
// kf is already A-layout (row=lc=key), qf already B-layout: swap is free.
// Ps swizzle: 8B-chunk c -> c ^ (2*(lc&7)) (even mask keeps b64/b128 align).
// Write groups (16 lanes/b64-cycle): 8 distinct chunk-pairs x 2 rows = 2-way
// (free, m136). pa b128 read groups (8 lanes): 8 distinct 16B chunks =
// conflict-free. rs becomes per-lane scalar (own q=lc); epilogue reduces
// across quads (2 shfl_xor) + 4 indexed shfl for the o-row normalizers.
__global__ __launch_bounds__(256, 2) void flash_kernel(const u16* __restrict__ qkv,
    const u16* __restrict__ kb, const u16* __restrict__ vtb, u16* __restrict__ yb) {
  __shared__ u16 Ks[2][64*128];          // 2 x 16 KB
  __shared__ u16 Vs[2][128*64];          // 2 x 16 KB
  __shared__ u16 Ps[4][16*64];           // 4 x 2 KB (8B-chunk XOR swizzled)
  const int tid = threadIdx.x;
  const int w = tid >> 6, lane = tid & 63;
  const int quad = lane >> 4, lc = lane & 15;
  const int bkv = blockIdx.x & 7;        // XCD-pinned (b,kv)
  const int r_  = blockIdx.x >> 3;       // 0..127
  const int b = bkv >> 2, kv = bkv & 3;
  const int h = kv*4 + w;                // wave = one head of the group
  const int qbase = (127 - r_)*16;       // heavy q-tiles dispatch first

  bf16x8 qf[4];
  {
    const u16* qp = qkv + (size_t)(b*T_SEQ + qbase + lc)*QKVN + h*HD + quad*8;
#pragma unroll
    for (int ks = 0; ks < 4; ++ks) qf[ks] = ld_bf8(qp + ks*32);
  }

  f32x4 o[8] = {};
  float rs = 0.f;                        // per-lane: running denom for q=qbase+lc
  const u16* kbase = kb  + (size_t)b*T_SEQ*KVD + kv*HD;
  const u16* vbase = vtb + (size_t)bkv*HD*T_SEQ;
  const int nk = qbase + 16;
  const int nt = (nk + 63) >> 6;
  const float cs = 0.08838834764831845f * 1.4426950408889634f;  // scale * log2(e)
  u16* pw = Ps[w];
  const int qv = qbase + lc;             // this lane's query index

  const u16* kptr[4];
  const u16* vptr[4];
#pragma unroll
  for (int rr = 0; rr < 4; ++rr) {
    int krow = (rr*4 + w)*4 + (lane >> 4);
    int kcc  = (lane & 15) ^ (krow & 15);
    kptr[rr] = kbase + (size_t)krow*KVD + kcc*8;
    int vrow = (rr*4 + w)*8 + (lane >> 3);
    int vcc  = (lane & 7) ^ (vrow & 7);
    vptr[rr] = vbase + (size_t)vrow*T_SEQ + vcc*8;
  }

  int koff[4], voff[2], poff[2], wbase[4];
#pragma unroll
  for (int ks = 0; ks < 4; ++ks) koff[ks] = lc*128 + (((ks*4 + quad) ^ lc)*8);
#pragma unroll
  for (int ks = 0; ks < 2; ++ks) voff[ks] = lc*64 + (((ks*4 + quad) ^ (lc & 7))*8);
  // Ps: row q=lc (64 u16 = 16 8B-chunks), chunk swizzle c ^= 2*(lc&7)
#pragma unroll
  for (int ks = 0; ks < 2; ++ks) poff[ks]  = lc*64 + (((8*ks + 2*quad) ^ (2*(lc & 7)))*4);
#pragma unroll
  for (int n2 = 0; n2 < 4; ++n2) wbase[n2] = lc*64 + (((4*n2 + quad) ^ (2*(lc & 7)))*4);

#pragma unroll
  for (int rr = 0; rr < 4; ++rr) glds16(kptr[rr], &Ks[0][(rr*4 + w)*512]);
#pragma unroll
  for (int rr = 0; rr < 4; ++rr) glds16(vptr[rr], &Vs[0][(rr*4 + w)*512]);
  asm volatile("s_waitcnt vmcnt(0)" ::: "memory");
  __builtin_amdgcn_sched_barrier(0);
  __builtin_amdgcn_s_barrier();
  __builtin_amdgcn_sched_barrier(0);

  for (int t = 0; t < nt; ++t) {
    const int cur = t & 1;
    if (t + 1 < nt) {
#pragma unroll
      for (int rr = 0; rr < 4; ++rr)
        glds16(kptr[rr] + (size_t)(t+1)*64*KVD, &Ks[cur^1][(rr*4 + w)*512]);
#pragma unroll
      for (int rr = 0; rr < 4; ++rr)
        glds16(vptr[rr] + (size_t)(t+1)*64,     &Vs[cur^1][(rr*4 + w)*512]);
    }
    const u16* ksb = Ks[cur];
    const u16* vsb = Vs[cur];
    const int k0 = t*64;

    // S^T = K Q^T : rows = keys (16nt2+4quad+r), cols = queries (lc)
    f32x4 sc[4] = {};
    __builtin_amdgcn_s_setprio(1);
#pragma unroll
    for (int nt2 = 0; nt2 < 4; ++nt2)
#pragma unroll
      for (int ks = 0; ks < 4; ++ks) {
        bf16x8 kf = ld_bf8(ksb + nt2*16*128 + koff[ks]);
        sc[nt2] = __builtin_amdgcn_mfma_f32_16x16x32_bf16(kf, qf[ks], sc[nt2], 0, 0, 0);
      }
    __builtin_amdgcn_s_setprio(0);

    // softmax (m=0): p = exp2(s*cs); lane owns q=qv, 4 adjacent keys per nt2
    if (k0 + 63 > qbase) {
#pragma unroll
      for (int nt2 = 0; nt2 < 4; ++nt2) {
        int kb0 = k0 + nt2*16 + quad*4;
        ushort4 pk;
#pragma unroll
        for (int r = 0; r < 4; ++r) {
          float e = __builtin_amdgcn_exp2f(sc[nt2][r]*cs);
          float p = (kb0 + r <= qv) ? e : 0.0f;
          rs += p;
          ((u16*)&pk)[r] = f2b(p);
        }
        *(ushort4*)(pw + wbase[nt2]) = pk;
      }
    } else {
#pragma unroll
      for (int nt2 = 0; nt2 < 4; ++nt2) {
        ushort4 pk;
#pragma unroll
        for (int r = 0; r < 4; ++r) {
          float p = __builtin_amdgcn_exp2f(sc[nt2][r]*cs);
          rs += p;
          ((u16*)&pk)[r] = f2b(p);
        }
        *(ushort4*)(pw + wbase[nt2]) = pk;
      }
    }

    // P: already [q][k] in Ps; read A-frags (intra-wave DS in-order)
    bf16x8 pa[2];
#pragma unroll
    for (int ks = 0; ks < 2; ++ks)
      pa[ks] = ld_bf8(pw + poff[ks]);

    // O += P V
    __builtin_amdgcn_s_setprio(1);
#pragma unroll
    for (int j = 0; j < 8; ++j)
#pragma unroll
      for (int ks = 0; ks < 2; ++ks) {
        bf16x8 vf = ld_bf8(vsb + j*16*64 + voff[ks]);
        o[j] = __builtin_amdgcn_mfma_f32_16x16x32_bf16(pa[ks], vf, o[j], 0, 0, 0);
      }
    __builtin_amdgcn_s_setprio(0);

    asm volatile("s_waitcnt vmcnt(0)" ::: "memory");
    __builtin_amdgcn_sched_barrier(0);
    __builtin_amdgcn_s_barrier();
    __builtin_amdgcn_sched_barrier(0);
  }

  // epilogue: total denom per q — reduce the 4 quad-partials of q=lc, then
  // fetch the normalizer for each o-row (q = quad*4 + r) via indexed shfl
  float rt = rs;
  rt += __shfl_xor(rt, 16);
  rt += __shfl_xor(rt, 32);
#pragma unroll
  for (int r = 0; r < 4; ++r) {
    float inv = 1.0f / __shfl(rt, quad*4 + r);
    size_t orow = (size_t)(b*T_SEQ + qbase + quad*4 + r)*EMB + h*HD;
#pragma unroll
    for (int j = 0; j < 8; ++j)
      yb[orow + j*16 + lc] = f2b(o[j][r]*inv);
  }
}

extern "C" void kernel_launch(void* const* d_in, const int* in_sizes, int n_in,
                              void* d_out, int out_size, void* d_ws, size_t ws_size,
                              hipStream_t stream) {
  const float* x      = (const float*)d_in[0];
  const float* W_attn = (const float*)d_in[1];
  const float* b_attn = (const float*)d_in[2];
  const float* W_proj = (const float*)d_in[3];
  const float* fc     = (const float*)d_in[4];
  const float* fs     = (const float*)d_in[5];

  u16* ws   = (u16*)d_ws;
  u16* xb   = ws;                          // 8.39M elems  (later aliased by yb)
  u16* WaT  = xb   + (size_t)MROWS*EMB;    // 6.29M        (later aliased by WpT)
  u16* qkv  = WaT  + (size_t)QKVN*EMB;     // 12.58M
  u16* kbuf = qkv  + (size_t)MROWS*QKVN;   // 2.10M
  u16* vtb  = kbuf + (size_t)MROWS*KVD;    // 2.10M
  u16* WpT  = WaT;   // W_attn^T dead after gemm1
  u16* yb   = xb;    // x_bf16 dead after gemm1
  float* out = (float*)d_out;

  // 1) fused prep: cvt_x + W_attn transpose
  prep_kernel<<<CVT_BLKS + TW1_BLKS, 256, 0, stream>>>(
      (const float4*)x, (ushort4*)xb, W_attn, WaT);
  // 2) gemm1: 256x192 tiles -> 256 blocks; 2-phase, NF=3, SB=3, vmcnt(5)
  gemm_kernel<192, 3, 3, 5, true>
      <<<dim3(QKVN/192, MROWS/256), 512, 0, stream>>>(
      xb, WaT, b_attn, qkv, MROWS, QKVN, EMB);
  // 3) fused: rope(K,V)+V-transpose + W_proj transpose
  ropetv_kernel<<<RTV_BLKS + TW2_BX*(EMB/64), 256, 0, stream>>>(
      qkv, fc, fs, kbuf, vtb, W_proj, WpT);
  // 4) flash v10: swapped QK^T + packed P-writes
  flash_kernel<<<dim3(B_SZ*NKV*(T_SEQ/16)), 256, 0, stream>>>(qkv, kbuf, vtb, yb);
  // 5) gemm2: 256x128 tiles -> 256 blocks; 2-phase, NF=2, SB=2, vmcnt(4)
  gemm_kernel<128, 2, 2, 4, false>
      <<<dim3(EMB/128, MROWS/256), 512, 0, stream>>>(
      yb, WpT, nullptr, out, MROWS, EMB, EMB);
}